// Round 1
// 307.511 us; speedup vs baseline: 1.0249x; 1.0249x over previous
//
#include <hip/hip_runtime.h>
#include <hip/hip_bf16.h>
#include <cstdint>

// ============================================================================
// MultiHeadSelfAttention: B=8 T=1024 D=1024 H=16 dh=64. fp32 in / fp32 out.
// R8: attn occupancy/amortization restructure (R7 counters: MfmaUtil 14%,
// VALUBusy 65%, Occupancy 28% -> resident-VALU-busy but barrier/staging
// overhead paid at QBLK=64 granularity, only ~2.2 blocks/CU resident):
//  - QBLK 64 -> 128: 512 threads, 8 waves x 16 q-rows. Per-wave inner loop
//    identical to R7; per work unit this halves barriers, K/V global
//    re-reads, LDS staging writes, and prefetch overhead. grid (16,8,8).
//  - L via ones-column MFMA: Lacc = mfma(P, ones) accumulates row sums
//    across all kt; removes 16 v_add/lane/kt and the epilogue shuffle
//    reduce; normalizer now consistent with the bf16 P used in PV.
//  - s_setprio(1) around both MFMA clusters (learn_hip m191: +4-7% attn).
//  LDS 36.0KB -> 4 blocks/CU cap (32 waves); VGPR ~72 unchanged.
// ws (64MiB): Qp@0, Kp@16MiB, Vt@32MiB, aout@48MiB (each [8192][1024] bf16).
// d_out scratch phase 1: ib_bf@0 (16MiB), wq_bf@16MiB (6MiB), bq_bf@22MiB.
// After attn: wo_bf/bo_bf overwrite dead Qp@0. GEMM3 writes d_out fp32 last.
// ============================================================================

using bf16 = __hip_bfloat16;
typedef __attribute__((ext_vector_type(8))) short short8;
typedef __attribute__((ext_vector_type(4))) short short4v;
typedef __attribute__((ext_vector_type(4))) float floatx4;

#define B_    8
#define T_    1024
#define D_    1024
#define H_    16
#define PROJW 3072

__device__ __forceinline__ void gl2lds16(const void* g, void* l) {
  __builtin_amdgcn_global_load_lds(
      (const __attribute__((address_space(1))) void*)g,
      (__attribute__((address_space(3))) void*)l,
      16, 0, 0);
}

__device__ __forceinline__ unsigned short f2b_bits(float f) {
  return __builtin_bit_cast(unsigned short, __float2bfloat16(f));
}

// ---------------------------------------------------------------------------
// fp32 -> bf16 elementwise convert (n multiple of 4), RNE
// ---------------------------------------------------------------------------
__global__ __launch_bounds__(256)
void cvt_f32_bf16(const float* __restrict__ src, bf16* __restrict__ dst, int n) {
  int i = (blockIdx.x * 256 + threadIdx.x) * 4;
  if (i < n) {
    floatx4 f = *(const floatx4*)(src + i);
    short4v h;
    h[0] = f2b_bits(f[0]); h[1] = f2b_bits(f[1]);
    h[2] = f2b_bits(f[2]); h[3] = f2b_bits(f[3]);
    *(short4v*)(dst + i) = h;
  }
}

// ---------------------------------------------------------------------------
// GEMM core: C = A[M,K] * Bm[N,K]^T + bias, bf16 DMA staging, fp32 accum.
// EPI=1: C fp32 (final output). EPI=2: QKV split epilogue (Qp/Kp token-major,
// Vt transposed [b][h][d][t]).
// 128x128 tile, BK=64, 4 waves x (64x64) of 16x16x32 MFMA.
// ---------------------------------------------------------------------------
template<int EPI>
__global__ __launch_bounds__(256)
void gemm_bt_bias(const bf16* __restrict__ A, const bf16* __restrict__ Bm,
                  const bf16* __restrict__ bias, void* __restrict__ C0,
                  void* __restrict__ C1, void* __restrict__ C2,
                  int M, int N, int K)
{
  __shared__ __align__(16) unsigned short sA[128 * 64];
  __shared__ __align__(16) unsigned short sB[128 * 64];

  const int tid  = threadIdx.x;
  const int lane = tid & 63;
  const int wv   = tid >> 6;
  const int quad = lane >> 4;
  const int l16  = lane & 15;
  const int wm   = wv >> 1, wn = wv & 1;
  const int bn   = blockIdx.x, bm = blockIdx.y;

  floatx4 acc[4][4];
#pragma unroll
  for (int i = 0; i < 4; ++i)
#pragma unroll
    for (int j = 0; j < 4; ++j) acc[i][j] = (floatx4){0.f, 0.f, 0.f, 0.f};

  const int o_base = wv * 1024 + lane * 16;   // byte offset within 16KB tile

  for (int kt = 0; kt < K; kt += 64) {
    __syncthreads();
#pragma unroll
    for (int it = 0; it < 4; ++it) {
      int o = it * 4096 + o_base;
      int row = o >> 7, col = (o & 127) >> 1;
      gl2lds16(A + (size_t)(bm * 128 + row) * K + kt + col,
               &sA[(it * 4096 + wv * 1024) >> 1]);
    }
#pragma unroll
    for (int it = 0; it < 4; ++it) {
      int o = it * 4096 + o_base;
      int row = o >> 7, col = (o & 127) >> 1;
      gl2lds16(Bm + (size_t)(bn * 128 + row) * K + kt + col,
               &sB[(it * 4096 + wv * 1024) >> 1]);
    }
    __syncthreads();

#pragma unroll
    for (int kk = 0; kk < 64; kk += 32) {
      short8 a_[4], b_[4];
#pragma unroll
      for (int i = 0; i < 4; ++i)
        a_[i] = *(const short8*)&sA[(wm * 64 + i * 16 + l16) * 64 + kk + quad * 8];
#pragma unroll
      for (int j = 0; j < 4; ++j)
        b_[j] = *(const short8*)&sB[(wn * 64 + j * 16 + l16) * 64 + kk + quad * 8];
#pragma unroll
      for (int i = 0; i < 4; ++i)
#pragma unroll
        for (int j = 0; j < 4; ++j)
          acc[i][j] = __builtin_amdgcn_mfma_f32_16x16x32_bf16(a_[i], b_[j], acc[i][j], 0, 0, 0);
    }
  }

  if (EPI == 1) {
    // final projection: fp32 C0[M,N]
#pragma unroll
    for (int j = 0; j < 4; ++j) {
      const int colg = bn * 128 + wn * 64 + j * 16 + l16;
      const float bv = __bfloat162float(bias[colg]);
#pragma unroll
      for (int i = 0; i < 4; ++i)
#pragma unroll
        for (int r = 0; r < 4; ++r) {
          int rowg = bm * 128 + wm * 64 + i * 16 + quad * 4 + r;
          ((float*)C0)[(size_t)rowg * N + colg] = acc[i][j][r] + bv;
        }
    }
  } else {
    // QKV split: bn 0..7 -> Qp (C0), 8..15 -> Kp (C1), 16..23 -> Vt (C2)
    const int region = bn >> 3;
    if (region < 2) {
      bf16* dst = (bf16*)(region == 0 ? C0 : C1);
#pragma unroll
      for (int j = 0; j < 4; ++j) {
        const int colg = bn * 128 + wn * 64 + j * 16 + l16;        // 0..3071
        const int colr = colg & 1023;                              // col in region
        const float bv = __bfloat162float(bias[colg]);
#pragma unroll
        for (int i = 0; i < 4; ++i)
#pragma unroll
          for (int r = 0; r < 4; ++r) {
            int rowg = bm * 128 + wm * 64 + i * 16 + quad * 4 + r;
            dst[(size_t)rowg * 1024 + colr] = __float2bfloat16(acc[i][j][r] + bv);
          }
      }
    } else {
      // V transposed: Vt[(b*16+h)<<16 | d*1024 | t], r-packed b64 stores
      bf16* vt = (bf16*)C2;
#pragma unroll
      for (int j = 0; j < 4; ++j) {
        const int colg = bn * 128 + wn * 64 + j * 16 + l16;
        const int d  = colg & 63;
        const int hh = (colg >> 6) & 15;
        const float bv = __bfloat162float(bias[colg]);
#pragma unroll
        for (int i = 0; i < 4; ++i) {
          int rowg0 = bm * 128 + wm * 64 + i * 16 + quad * 4;
          int bb = rowg0 >> 10, t0 = rowg0 & 1023;
          short4v pk;
#pragma unroll
          for (int r = 0; r < 4; ++r) pk[r] = (short)f2b_bits(acc[i][j][r] + bv);
          *(short4v*)&vt[((size_t)(bb * 16 + hh) << 16) + ((size_t)d << 10) + t0] = pk;
        }
      }
    }
  }
}

// ---------------------------------------------------------------------------
// Fused attention. R8: grid = (H, T/128, B), 512 threads (8 waves x 16 rows),
// LDS 36.0KB. Q fragments in registers (loop-invariant). K and V^T
// register-staged into stride-72 LDS (balanced banks), software-pipelined
// across kt. Each thread stages exactly one 16B chunk of sK and one of sVT.
// sigma(n)=(n&15)*4+(n>>4) on K rows => logical score col = l16*4+j:
// float4 adj/mask loads, b64 sP stores. p=exp2(clamped z).
// L row-sums via ones-column MFMA accumulated across kt (no VALU L adds,
// no epilogue shuffle reduce; normalizer consistent with bf16 P).
// ---------------------------------------------------------------------------
__global__ __launch_bounds__(512)
void attn_fused(const bf16* __restrict__ Qp, const bf16* __restrict__ Kp,
                const bf16* __restrict__ Vt, const float* __restrict__ adj,
                const float* __restrict__ mask, bf16* __restrict__ aout)
{
  __shared__ __align__(16) unsigned short sK[64 * 72];
  __shared__ __align__(16) unsigned short sVT[64 * 72];
  __shared__ __align__(16) unsigned short sP[128 * 72];

  const int tid  = threadIdx.x;
  const int lane = tid & 63;
  const int wv   = tid >> 6;          // 0..7
  const int quad = lane >> 4;
  const int l16  = lane & 15;
  const int h = blockIdx.x, qt = blockIdx.y, b = blockIdx.z;

  // Q fragments: rows qt*128 + wv*16 + l16, k = kk + quad*8 + [0..7]
  const bf16* qbase = Qp + (size_t)(b * T_ + qt * 128 + wv * 16 + l16) * 1024 + h * 64 + quad * 8;
  const short8 aq0 = *(const short8*)qbase;
  const short8 aq1 = *(const short8*)(qbase + 32);

  // staging: 512 threads cover 64 rows x 8 chunks, one 16B chunk each
  const int srow  = tid >> 3;                          // 0..63
  const int chunk = (tid & 7) * 8;
  const int sig = ((srow & 15) << 2) | (srow >> 4);    // token offset for sK row
  const bf16* kb = Kp + (size_t)(b * T_ + sig) * 1024 + h * 64 + chunk;  // +kt<<16
  const bf16* vb = Vt + ((size_t)(b * 16 + h) << 16) + ((size_t)srow << 10) + chunk; // +kt*64

  // adj/mask row pointers
  const float* mb = mask + b * T_ + l16 * 4;
  const float* adjr[4];
#pragma unroll
  for (int r = 0; r < 4; ++r)
    adjr[r] = adj + ((size_t)b * T_ + qt * 128 + wv * 16 + quad * 4 + r) * T_ + l16 * 4;

  // preload kt=0 staging registers
  short8 kr = *(const short8*)kb;
  short8 vr = *(const short8*)vb;

  // bf16 1.0 fragment for L row-sums via MFMA
  short8 ones8;
#pragma unroll
  for (int i = 0; i < 8; ++i) ones8[i] = (short)0x3F80;

  floatx4 oacc[4];
#pragma unroll
  for (int d = 0; d < 4; ++d) oacc[d] = (floatx4){0.f, 0.f, 0.f, 0.f};
  floatx4 Lacc = (floatx4){0.f, 0.f, 0.f, 0.f};

  const float SC = 0.125f * 1.44269504088896f;   // (1/sqrt(dh)) * log2(e)

  for (int kt = 0; kt < 16; ++kt) {
    // adj/mask for this tile (logical cols kt*64 + l16*4 + {0..3})
    floatx4 av[4];
    floatx4 mk4 = *(const floatx4*)(mb + kt * 64);
#pragma unroll
    for (int r = 0; r < 4; ++r) av[r] = *(const floatx4*)(adjr[r] + kt * 64);
    float cj[4], off[4];
#pragma unroll
    for (int j = 0; j < 4; ++j) {
      cj[j]  = mk4[j] * SC;
      off[j] = (mk4[j] == 0.f) ? -1e30f : 0.f;
    }

    __syncthreads();   // sync1: all waves done reading sK/sVT of prev kt
    *(short8*)&sK [srow * 72 + chunk] = kr;
    *(short8*)&sVT[srow * 72 + chunk] = vr;
    __syncthreads();   // sync2: staging visible

    // prefetch next kt's staging registers (VMEM overlaps compute below)
    {
      int nk = kt < 15 ? kt + 1 : 15;
      kr = *(const short8*)(kb + ((size_t)nk << 16));
      vr = *(const short8*)(vb + (nk << 6));
    }

    // S = Q K^T  (sacc[j][r]: row wv*16+quad*4+r, logical col l16*4+j)
    floatx4 sacc[4];
#pragma unroll
    for (int j = 0; j < 4; ++j) sacc[j] = (floatx4){0.f, 0.f, 0.f, 0.f};
    __builtin_amdgcn_s_setprio(1);
#pragma unroll
    for (int kk = 0; kk < 64; kk += 32) {
      short8 aq = kk ? aq1 : aq0;
#pragma unroll
      for (int j = 0; j < 4; ++j) {
        short8 bk = *(const short8*)&sK[(j * 16 + l16) * 72 + kk + quad * 8];
        sacc[j] = __builtin_amdgcn_mfma_f32_16x16x32_bf16(aq, bk, sacc[j], 0, 0, 0);
      }
    }
    __builtin_amdgcn_s_setprio(0);

    // p = exp2(clamp(z)), pack + b64 store (L comes from MFMA below)
#pragma unroll
    for (int r = 0; r < 4; ++r) {
      short4v ph;
#pragma unroll
      for (int j = 0; j < 4; ++j) {
        float t = sacc[j][r] * av[r][j];
        float z = fminf(fmaf(t, cj[j], off[j]), 100.f);
        float p = exp2f(z);
        unsigned bits = __builtin_bit_cast(unsigned, p);
        ph[j] = (short)((bits + 0x8000u) >> 16);
      }
      *(short4v*)&sP[(wv * 16 + quad * 4 + r) * 72 + l16 * 4] = ph;
    }

    // sP rows wave-local; same-wave DS is HW-ordered. Stop compiler reorder:
    __asm__ __volatile__("" ::: "memory");

    // O += P V ; L += P * ones
    __builtin_amdgcn_s_setprio(1);
#pragma unroll
    for (int kk = 0; kk < 64; kk += 32) {
      short8 ap = *(const short8*)&sP[(wv * 16 + l16) * 72 + kk + quad * 8];
      Lacc = __builtin_amdgcn_mfma_f32_16x16x32_bf16(ap, ones8, Lacc, 0, 0, 0);
#pragma unroll
      for (int d = 0; d < 4; ++d) {
        short8 bv = *(const short8*)&sVT[(d * 16 + l16) * 72 + kk + quad * 8];
        oacc[d] = __builtin_amdgcn_mfma_f32_16x16x32_bf16(ap, bv, oacc[d], 0, 0, 0);
      }
    }
    __builtin_amdgcn_s_setprio(0);
  }

  // epilogue: Lacc[r] already holds the full row sum (every col identical)
#pragma unroll
  for (int d = 0; d < 4; ++d) {
#pragma unroll
    for (int r = 0; r < 4; ++r) {
      int qrow = qt * 128 + wv * 16 + quad * 4 + r;
      float val = oacc[d][r] / (Lacc[r] + 1e-13f);
      aout[(size_t)(b * T_ + qrow) * 1024 + h * 64 + d * 16 + l16] = __float2bfloat16(val);
    }
  }
}

// ---------------------------------------------------------------------------
extern "C" void kernel_launch(void* const* d_in, const int* in_sizes, int n_in,
                              void* d_out, int out_size, void* d_ws, size_t ws_size,
                              hipStream_t stream) {
  const float* inputs = (const float*)d_in[0];   // [8,1024,1024]
  const float* mask   = (const float*)d_in[1];   // [8,1024]
  const float* adj    = (const float*)d_in[2];   // [8,1024,1024]
  const float* W_qkv  = (const float*)d_in[3];   // [3072,1024]
  const float* b_qkv  = (const float*)d_in[4];   // [3072]
  const float* W_out  = (const float*)d_in[5];   // [1024,1024]
  const float* b_out  = (const float*)d_in[6];   // [1024]

  const size_t SEG = (size_t)8192 * 1024;        // 16 MiB bf16 segments
  bf16* Qp   = (bf16*)d_ws;                      // @0
  bf16* Kp   = Qp + SEG;                         // @16MiB
  bf16* Vt   = Kp + SEG;                         // @32MiB
  bf16* aout = Vt + SEG;                         // @48MiB
  bf16* wo_bf = Qp;                              // Qp dead after attn
  bf16* bo_bf = Qp + (size_t)1024 * 1024;

  // d_out as phase-1 scratch (32MiB fp32 region, dead until GEMM3)
  bf16* ib_bf = (bf16*)d_out;                    // 16MiB
  bf16* wq_bf = ib_bf + SEG;                     // 6MiB
  bf16* bq_bf = wq_bf + (size_t)3072 * 1024;

  dim3 blk(256);
  cvt_f32_bf16<<<dim3(8192 * 1024 / 4 / 256), blk, 0, stream>>>(inputs, ib_bf, 8192 * 1024);
  cvt_f32_bf16<<<dim3(3072 * 1024 / 4 / 256), blk, 0, stream>>>(W_qkv, wq_bf, 3072 * 1024);
  cvt_f32_bf16<<<dim3(3), blk, 0, stream>>>(b_qkv, bq_bf, 3072);
  // QKV projection with split epilogue (Qp, Kp, Vt)
  gemm_bt_bias<2><<<dim3(PROJW / 128, (B_ * T_) / 128), blk, 0, stream>>>(
      ib_bf, wq_bf, bq_bf, Qp, Kp, Vt, B_ * T_, PROJW, D_);
  // fused attention (R8: 512 threads, 128 q-rows/block)
  attn_fused<<<dim3(H_, T_ / 128, B_), dim3(512), 0, stream>>>(Qp, Kp, Vt, adj, mask, aout);
  // output projection weights into dead Qp region
  cvt_f32_bf16<<<dim3(1024 * 1024 / 4 / 256), blk, 0, stream>>>(W_out, wo_bf, 1024 * 1024);
  cvt_f32_bf16<<<dim3(1), blk, 0, stream>>>(b_out, bo_bf, 1024);
  // output projection: C fp32 -> d_out
  gemm_bt_bias<1><<<dim3(D_ / 128, (B_ * T_) / 128), blk, 0, stream>>>(
      aout, wo_bf, bo_bf, d_out, nullptr, nullptr, B_ * T_, D_, D_);
}

// Round 2
// 286.367 us; speedup vs baseline: 1.1005x; 1.0738x over previous
//
#include <hip/hip_runtime.h>
#include <hip/hip_bf16.h>
#include <cstdint>

// ============================================================================
// MultiHeadSelfAttention: B=8 T=1024 D=1024 H=16 dh=64. fp32 in / fp32 out.
// R9: GEMM K-loop restructure (R8 counters: GEMM1 93us @554TF, MfmaUtil 22%,
// VALUBusy 25%, HBM 17% -> latency/drain-bound; LDS_BANK_CONFLICT 18.9M
// (~33% of cycles) from 16-way conflicts on stride-128B fragment reads;
// FETCH 77MB vs 22MB ideal from XCD round-robin):
//  - double-buffered LDS (2x32KB slots), stage of tile t+1 issued one full
//    K-tile ahead; counted s_waitcnt vmcnt(8) (never 0 in loop) + raw
//    s_barrier (no compiler vmcnt(0) drain). All LDS writes are gl2lds
//    (vmcnt-tracked), no ds_writes -> raw barriers safe.
//  - T2 both-sides XOR swizzle (rule #21): LDS dest linear, global source
//    pre-swizzled col ^= ((row&7)<<4) bytes, fragment reads apply
//    (kk+quad*8) ^ ((l16&7)<<3). 16-way -> 2-way (free).
//  - T1 XCD-chunked block swizzle (grids 1536/512, both %8==0).
//  Epilogues and fragment geometry unchanged from R8.
// ws (64MiB): Qp@0, Kp@16MiB, Vt@32MiB, aout@48MiB (each [8192][1024] bf16).
// d_out scratch phase 1: ib_bf@0 (16MiB), wq_bf@16MiB (6MiB), bq_bf@22MiB.
// After attn: wo_bf/bo_bf overwrite dead Qp@0. GEMM3 writes d_out fp32 last.
// ============================================================================

using bf16 = __hip_bfloat16;
typedef __attribute__((ext_vector_type(8))) short short8;
typedef __attribute__((ext_vector_type(4))) short short4v;
typedef __attribute__((ext_vector_type(4))) float floatx4;

#define B_    8
#define T_    1024
#define D_    1024
#define H_    16
#define PROJW 3072

__device__ __forceinline__ void gl2lds16(const void* g, void* l) {
  __builtin_amdgcn_global_load_lds(
      (const __attribute__((address_space(1))) void*)g,
      (__attribute__((address_space(3))) void*)l,
      16, 0, 0);
}

__device__ __forceinline__ unsigned short f2b_bits(float f) {
  return __builtin_bit_cast(unsigned short, __float2bfloat16(f));
}

// ---------------------------------------------------------------------------
// fp32 -> bf16 elementwise convert (n multiple of 4), RNE
// ---------------------------------------------------------------------------
__global__ __launch_bounds__(256)
void cvt_f32_bf16(const float* __restrict__ src, bf16* __restrict__ dst, int n) {
  int i = (blockIdx.x * 256 + threadIdx.x) * 4;
  if (i < n) {
    floatx4 f = *(const floatx4*)(src + i);
    short4v h;
    h[0] = f2b_bits(f[0]); h[1] = f2b_bits(f[1]);
    h[2] = f2b_bits(f[2]); h[3] = f2b_bits(f[3]);
    *(short4v*)(dst + i) = h;
  }
}

// ---------------------------------------------------------------------------
// GEMM core: C = A[M,K] * Bm[N,K]^T + bias, bf16 DMA staging, fp32 accum.
// EPI=1: C fp32 (final output). EPI=2: QKV split epilogue (Qp/Kp token-major,
// Vt transposed [b][h][d][t]).
// 128x128 tile, BK=64, 4 waves x (64x64) of 16x16x32 MFMA.
// R9 loop: dbuf slots, deep prefetch, counted vmcnt(8), raw barriers,
// T2 swizzle (source-side + read-side), T1 XCD block chunking.
// ---------------------------------------------------------------------------
template<int EPI>
__global__ __launch_bounds__(256)
void gemm_bt_bias(const bf16* __restrict__ A, const bf16* __restrict__ Bm,
                  const bf16* __restrict__ bias, void* __restrict__ C0,
                  void* __restrict__ C1, void* __restrict__ C2,
                  int M, int N, int K)
{
  __shared__ __align__(16) unsigned short sA[2][128 * 64];
  __shared__ __align__(16) unsigned short sB[2][128 * 64];

  const int tid  = threadIdx.x;
  const int lane = tid & 63;
  const int wv   = tid >> 6;
  const int quad = lane >> 4;
  const int l16  = lane & 15;
  const int wm   = wv >> 1, wn = wv & 1;

  // T1: XCD-chunked block swizzle. nwg % 8 == 0 for both launches (1536/512).
  const int gx   = gridDim.x;
  const int nwg  = gx * gridDim.y;
  const int bidl = blockIdx.y * gx + blockIdx.x;
  const int swzb = (bidl & 7) * (nwg >> 3) + (bidl >> 3);
  const int bn   = swzb % gx, bm = swzb / gx;

  floatx4 acc[4][4];
#pragma unroll
  for (int i = 0; i < 4; ++i)
#pragma unroll
    for (int j = 0; j < 4; ++j) acc[i][j] = (floatx4){0.f, 0.f, 0.f, 0.f};

  // staging geometry: thread covers LDS bytes o = it*4096 + wv*1024 + lane*16.
  // LDS dest stays LINEAR (gl2lds: wave base + lane*16). Global source is
  // pre-swizzled: col_byte = (o&127) ^ ((row&7)<<4)  (involution, rule #21).
  const int o_base = wv * 1024 + lane * 16;
  const bf16* gA[4];
  const bf16* gB[4];
#pragma unroll
  for (int it = 0; it < 4; ++it) {
    int o   = it * 4096 + o_base;
    int row = o >> 7;
    int col = ((o & 127) ^ ((row & 7) << 4)) >> 1;
    gA[it] = A  + (size_t)(bm * 128 + row) * K + col;
    gB[it] = Bm + (size_t)(bn * 128 + row) * K + col;
  }

  const int NT = K >> 6;
  // prologue: stage tile 0 -> slot 0
#pragma unroll
  for (int it = 0; it < 4; ++it)
    gl2lds16(gA[it], &sA[0][(it * 4096 + wv * 1024) >> 1]);
#pragma unroll
  for (int it = 0; it < 4; ++it)
    gl2lds16(gB[it], &sB[0][(it * 4096 + wv * 1024) >> 1]);

  const int swx = (l16 & 7) << 3;   // read-side element XOR (rows: row&7 == l16&7)

  for (int t = 0; t < NT; ++t) {
    const int s = t & 1;
    if (t + 1 < NT) {
      // stage tile t+1 -> slot s^1 (last read in compute(t-1), before barrier2)
#pragma unroll
      for (int it = 0; it < 4; ++it)
        gl2lds16(gA[it] + (size_t)(t + 1) * 64, &sA[s ^ 1][(it * 4096 + wv * 1024) >> 1]);
#pragma unroll
      for (int it = 0; it < 4; ++it)
        gl2lds16(gB[it] + (size_t)(t + 1) * 64, &sB[s ^ 1][(it * 4096 + wv * 1024) >> 1]);
      __builtin_amdgcn_sched_barrier(0);
      // outstanding = 8 (tile t) + 8 (tile t+1); wait the oldest 8 only.
      asm volatile("s_waitcnt vmcnt(8)" ::: "memory");
    } else {
      asm volatile("s_waitcnt vmcnt(0)" ::: "memory");
    }
    __builtin_amdgcn_s_barrier();        // barrier1: tile t visible to all
    __builtin_amdgcn_sched_barrier(0);

#pragma unroll
    for (int kk = 0; kk < 64; kk += 32) {
      short8 a_[4], b_[4];
#pragma unroll
      for (int i = 0; i < 4; ++i)
        a_[i] = *(const short8*)&sA[s][(wm * 64 + i * 16 + l16) * 64 + ((kk + quad * 8) ^ swx)];
#pragma unroll
      for (int j = 0; j < 4; ++j)
        b_[j] = *(const short8*)&sB[s][(wn * 64 + j * 16 + l16) * 64 + ((kk + quad * 8) ^ swx)];
#pragma unroll
      for (int i = 0; i < 4; ++i)
#pragma unroll
        for (int j = 0; j < 4; ++j)
          acc[i][j] = __builtin_amdgcn_mfma_f32_16x16x32_bf16(a_[i], b_[j], acc[i][j], 0, 0, 0);
    }

    __builtin_amdgcn_sched_barrier(0);
    __builtin_amdgcn_s_barrier();        // barrier2: all done reading slot s
  }

  if (EPI == 1) {
    // final projection: fp32 C0[M,N]
#pragma unroll
    for (int j = 0; j < 4; ++j) {
      const int colg = bn * 128 + wn * 64 + j * 16 + l16;
      const float bv = __bfloat162float(bias[colg]);
#pragma unroll
      for (int i = 0; i < 4; ++i)
#pragma unroll
        for (int r = 0; r < 4; ++r) {
          int rowg = bm * 128 + wm * 64 + i * 16 + quad * 4 + r;
          ((float*)C0)[(size_t)rowg * N + colg] = acc[i][j][r] + bv;
        }
    }
  } else {
    // QKV split: bn 0..7 -> Qp (C0), 8..15 -> Kp (C1), 16..23 -> Vt (C2)
    const int region = bn >> 3;
    if (region < 2) {
      bf16* dst = (bf16*)(region == 0 ? C0 : C1);
#pragma unroll
      for (int j = 0; j < 4; ++j) {
        const int colg = bn * 128 + wn * 64 + j * 16 + l16;        // 0..3071
        const int colr = colg & 1023;                              // col in region
        const float bv = __bfloat162float(bias[colg]);
#pragma unroll
        for (int i = 0; i < 4; ++i)
#pragma unroll
          for (int r = 0; r < 4; ++r) {
            int rowg = bm * 128 + wm * 64 + i * 16 + quad * 4 + r;
            dst[(size_t)rowg * 1024 + colr] = __float2bfloat16(acc[i][j][r] + bv);
          }
      }
    } else {
      // V transposed: Vt[(b*16+h)<<16 | d*1024 | t], r-packed b64 stores
      bf16* vt = (bf16*)C2;
#pragma unroll
      for (int j = 0; j < 4; ++j) {
        const int colg = bn * 128 + wn * 64 + j * 16 + l16;
        const int d  = colg & 63;
        const int hh = (colg >> 6) & 15;
        const float bv = __bfloat162float(bias[colg]);
#pragma unroll
        for (int i = 0; i < 4; ++i) {
          int rowg0 = bm * 128 + wm * 64 + i * 16 + quad * 4;
          int bb = rowg0 >> 10, t0 = rowg0 & 1023;
          short4v pk;
#pragma unroll
          for (int r = 0; r < 4; ++r) pk[r] = (short)f2b_bits(acc[i][j][r] + bv);
          *(short4v*)&vt[((size_t)(bb * 16 + hh) << 16) + ((size_t)d << 10) + t0] = pk;
        }
      }
    }
  }
}

// ---------------------------------------------------------------------------
// Fused attention. R8: grid = (H, T/128, B), 512 threads (8 waves x 16 rows),
// LDS 36.0KB. Q fragments in registers (loop-invariant). K and V^T
// register-staged into stride-72 LDS (balanced banks), software-pipelined
// across kt. Each thread stages exactly one 16B chunk of sK and one of sVT.
// sigma(n)=(n&15)*4+(n>>4) on K rows => logical score col = l16*4+j:
// float4 adj/mask loads, b64 sP stores. p=exp2(clamped z).
// L row-sums via ones-column MFMA accumulated across kt (no VALU L adds,
// no epilogue shuffle reduce; normalizer consistent with bf16 P).
// ---------------------------------------------------------------------------
__global__ __launch_bounds__(512)
void attn_fused(const bf16* __restrict__ Qp, const bf16* __restrict__ Kp,
                const bf16* __restrict__ Vt, const float* __restrict__ adj,
                const float* __restrict__ mask, bf16* __restrict__ aout)
{
  __shared__ __align__(16) unsigned short sK[64 * 72];
  __shared__ __align__(16) unsigned short sVT[64 * 72];
  __shared__ __align__(16) unsigned short sP[128 * 72];

  const int tid  = threadIdx.x;
  const int lane = tid & 63;
  const int wv   = tid >> 6;          // 0..7
  const int quad = lane >> 4;
  const int l16  = lane & 15;
  const int h = blockIdx.x, qt = blockIdx.y, b = blockIdx.z;

  // Q fragments: rows qt*128 + wv*16 + l16, k = kk + quad*8 + [0..7]
  const bf16* qbase = Qp + (size_t)(b * T_ + qt * 128 + wv * 16 + l16) * 1024 + h * 64 + quad * 8;
  const short8 aq0 = *(const short8*)qbase;
  const short8 aq1 = *(const short8*)(qbase + 32);

  // staging: 512 threads cover 64 rows x 8 chunks, one 16B chunk each
  const int srow  = tid >> 3;                          // 0..63
  const int chunk = (tid & 7) * 8;
  const int sig = ((srow & 15) << 2) | (srow >> 4);    // token offset for sK row
  const bf16* kb = Kp + (size_t)(b * T_ + sig) * 1024 + h * 64 + chunk;  // +kt<<16
  const bf16* vb = Vt + ((size_t)(b * 16 + h) << 16) + ((size_t)srow << 10) + chunk; // +kt*64

  // adj/mask row pointers
  const float* mb = mask + b * T_ + l16 * 4;
  const float* adjr[4];
#pragma unroll
  for (int r = 0; r < 4; ++r)
    adjr[r] = adj + ((size_t)b * T_ + qt * 128 + wv * 16 + quad * 4 + r) * T_ + l16 * 4;

  // preload kt=0 staging registers
  short8 kr = *(const short8*)kb;
  short8 vr = *(const short8*)vb;

  // bf16 1.0 fragment for L row-sums via MFMA
  short8 ones8;
#pragma unroll
  for (int i = 0; i < 8; ++i) ones8[i] = (short)0x3F80;

  floatx4 oacc[4];
#pragma unroll
  for (int d = 0; d < 4; ++d) oacc[d] = (floatx4){0.f, 0.f, 0.f, 0.f};
  floatx4 Lacc = (floatx4){0.f, 0.f, 0.f, 0.f};

  const float SC = 0.125f * 1.44269504088896f;   // (1/sqrt(dh)) * log2(e)

  for (int kt = 0; kt < 16; ++kt) {
    // adj/mask for this tile (logical cols kt*64 + l16*4 + {0..3})
    floatx4 av[4];
    floatx4 mk4 = *(const floatx4*)(mb + kt * 64);
#pragma unroll
    for (int r = 0; r < 4; ++r) av[r] = *(const floatx4*)(adjr[r] + kt * 64);
    float cj[4], off[4];
#pragma unroll
    for (int j = 0; j < 4; ++j) {
      cj[j]  = mk4[j] * SC;
      off[j] = (mk4[j] == 0.f) ? -1e30f : 0.f;
    }

    __syncthreads();   // sync1: all waves done reading sK/sVT of prev kt
    *(short8*)&sK [srow * 72 + chunk] = kr;
    *(short8*)&sVT[srow * 72 + chunk] = vr;
    __syncthreads();   // sync2: staging visible

    // prefetch next kt's staging registers (VMEM overlaps compute below)
    {
      int nk = kt < 15 ? kt + 1 : 15;
      kr = *(const short8*)(kb + ((size_t)nk << 16));
      vr = *(const short8*)(vb + (nk << 6));
    }

    // S = Q K^T  (sacc[j][r]: row wv*16+quad*4+r, logical col l16*4+j)
    floatx4 sacc[4];
#pragma unroll
    for (int j = 0; j < 4; ++j) sacc[j] = (floatx4){0.f, 0.f, 0.f, 0.f};
    __builtin_amdgcn_s_setprio(1);
#pragma unroll
    for (int kk = 0; kk < 64; kk += 32) {
      short8 aq = kk ? aq1 : aq0;
#pragma unroll
      for (int j = 0; j < 4; ++j) {
        short8 bk = *(const short8*)&sK[(j * 16 + l16) * 72 + kk + quad * 8];
        sacc[j] = __builtin_amdgcn_mfma_f32_16x16x32_bf16(aq, bk, sacc[j], 0, 0, 0);
      }
    }
    __builtin_amdgcn_s_setprio(0);

    // p = exp2(clamp(z)), pack + b64 store (L comes from MFMA below)
#pragma unroll
    for (int r = 0; r < 4; ++r) {
      short4v ph;
#pragma unroll
      for (int j = 0; j < 4; ++j) {
        float t = sacc[j][r] * av[r][j];
        float z = fminf(fmaf(t, cj[j], off[j]), 100.f);
        float p = exp2f(z);
        unsigned bits = __builtin_bit_cast(unsigned, p);
        ph[j] = (short)((bits + 0x8000u) >> 16);
      }
      *(short4v*)&sP[(wv * 16 + quad * 4 + r) * 72 + l16 * 4] = ph;
    }

    // sP rows wave-local; same-wave DS is HW-ordered. Stop compiler reorder:
    __asm__ __volatile__("" ::: "memory");

    // O += P V ; L += P * ones
    __builtin_amdgcn_s_setprio(1);
#pragma unroll
    for (int kk = 0; kk < 64; kk += 32) {
      short8 ap = *(const short8*)&sP[(wv * 16 + l16) * 72 + kk + quad * 8];
      Lacc = __builtin_amdgcn_mfma_f32_16x16x32_bf16(ap, ones8, Lacc, 0, 0, 0);
#pragma unroll
      for (int d = 0; d < 4; ++d) {
        short8 bv = *(const short8*)&sVT[(d * 16 + l16) * 72 + kk + quad * 8];
        oacc[d] = __builtin_amdgcn_mfma_f32_16x16x32_bf16(ap, bv, oacc[d], 0, 0, 0);
      }
    }
    __builtin_amdgcn_s_setprio(0);
  }

  // epilogue: Lacc[r] already holds the full row sum (every col identical)
#pragma unroll
  for (int d = 0; d < 4; ++d) {
#pragma unroll
    for (int r = 0; r < 4; ++r) {
      int qrow = qt * 128 + wv * 16 + quad * 4 + r;
      float val = oacc[d][r] / (Lacc[r] + 1e-13f);
      aout[(size_t)(b * T_ + qrow) * 1024 + h * 64 + d * 16 + l16] = __float2bfloat16(val);
    }
  }
}

// ---------------------------------------------------------------------------
extern "C" void kernel_launch(void* const* d_in, const int* in_sizes, int n_in,
                              void* d_out, int out_size, void* d_ws, size_t ws_size,
                              hipStream_t stream) {
  const float* inputs = (const float*)d_in[0];   // [8,1024,1024]
  const float* mask   = (const float*)d_in[1];   // [8,1024]
  const float* adj    = (const float*)d_in[2];   // [8,1024,1024]
  const float* W_qkv  = (const float*)d_in[3];   // [3072,1024]
  const float* b_qkv  = (const float*)d_in[4];   // [3072]
  const float* W_out  = (const float*)d_in[5];   // [1024,1024]
  const float* b_out  = (const float*)d_in[6];   // [1024]

  const size_t SEG = (size_t)8192 * 1024;        // 16 MiB bf16 segments
  bf16* Qp   = (bf16*)d_ws;                      // @0
  bf16* Kp   = Qp + SEG;                         // @16MiB
  bf16* Vt   = Kp + SEG;                         // @32MiB
  bf16* aout = Vt + SEG;                         // @48MiB
  bf16* wo_bf = Qp;                              // Qp dead after attn
  bf16* bo_bf = Qp + (size_t)1024 * 1024;

  // d_out as phase-1 scratch (32MiB fp32 region, dead until GEMM3)
  bf16* ib_bf = (bf16*)d_out;                    // 16MiB
  bf16* wq_bf = ib_bf + SEG;                     // 6MiB
  bf16* bq_bf = wq_bf + (size_t)3072 * 1024;

  dim3 blk(256);
  cvt_f32_bf16<<<dim3(8192 * 1024 / 4 / 256), blk, 0, stream>>>(inputs, ib_bf, 8192 * 1024);
  cvt_f32_bf16<<<dim3(3072 * 1024 / 4 / 256), blk, 0, stream>>>(W_qkv, wq_bf, 3072 * 1024);
  cvt_f32_bf16<<<dim3(3), blk, 0, stream>>>(b_qkv, bq_bf, 3072);
  // QKV projection with split epilogue (Qp, Kp, Vt)
  gemm_bt_bias<2><<<dim3(PROJW / 128, (B_ * T_) / 128), blk, 0, stream>>>(
      ib_bf, wq_bf, bq_bf, Qp, Kp, Vt, B_ * T_, PROJW, D_);
  // fused attention (512 threads, 128 q-rows/block)
  attn_fused<<<dim3(H_, T_ / 128, B_), dim3(512), 0, stream>>>(Qp, Kp, Vt, adj, mask, aout);
  // output projection weights into dead Qp region
  cvt_f32_bf16<<<dim3(1024 * 1024 / 4 / 256), blk, 0, stream>>>(W_out, wo_bf, 1024 * 1024);
  cvt_f32_bf16<<<dim3(1), blk, 0, stream>>>(b_out, bo_bf, 1024);
  // output projection: C fp32 -> d_out
  gemm_bt_bias<1><<<dim3(D_ / 128, (B_ * T_) / 128), blk, 0, stream>>>(
      aout, wo_bf, bo_bf, d_out, nullptr, nullptr, B_ * T_, D_, D_);
}

// Round 3
// 284.798 us; speedup vs baseline: 1.1066x; 1.0055x over previous
//
#include <hip/hip_runtime.h>
#include <hip/hip_bf16.h>
#include <cstdint>

// ============================================================================
// MultiHeadSelfAttention: B=8 T=1024 D=1024 H=16 dh=64. fp32 in / fp32 out.
// R10: attn softmax VALU cut (R9 counters: attn 89us, VALUBusy 60%,
// MfmaUtil 18% -> VALU-bound; ~40 of ~104 VALU ops/kt/lane were the manual
// bf16 round+pack):
//  - pack P via v_cvt_pk_bf16_f32 (2 f32 -> packed 2 bf16, RNE, 1 op/pair;
//    T12 primitive) -> 8 ops replace ~40 (add/shift/perm) per kt.
//  - fold SC*mask into avc = av[r]*cjv vector mul (pk-pairable), removing
//    the separate per-element t=sacc*av mul.
//  GEMMs, staging, barriers, epilogues identical to R9.
// R9 recap: GEMM dbuf + counted vmcnt(8) + raw barriers + T2 both-sides
// swizzle + T1 XCD chunking; attn 512thr/128 q-rows, ones-MFMA L, setprio.
// ws (64MiB): Qp@0, Kp@16MiB, Vt@32MiB, aout@48MiB (each [8192][1024] bf16).
// d_out scratch phase 1: ib_bf@0 (16MiB), wq_bf@16MiB (6MiB), bq_bf@22MiB.
// After attn: wo_bf/bo_bf overwrite dead Qp@0. GEMM3 writes d_out fp32 last.
// ============================================================================

using bf16 = __hip_bfloat16;
typedef __attribute__((ext_vector_type(8))) short short8;
typedef __attribute__((ext_vector_type(4))) short short4v;
typedef __attribute__((ext_vector_type(4))) float floatx4;
typedef __attribute__((ext_vector_type(2))) unsigned int uint2v;

#define B_    8
#define T_    1024
#define D_    1024
#define H_    16
#define PROJW 3072

__device__ __forceinline__ void gl2lds16(const void* g, void* l) {
  __builtin_amdgcn_global_load_lds(
      (const __attribute__((address_space(1))) void*)g,
      (__attribute__((address_space(3))) void*)l,
      16, 0, 0);
}

__device__ __forceinline__ unsigned short f2b_bits(float f) {
  return __builtin_bit_cast(unsigned short, __float2bfloat16(f));
}

// ---------------------------------------------------------------------------
// fp32 -> bf16 elementwise convert (n multiple of 4), RNE
// ---------------------------------------------------------------------------
__global__ __launch_bounds__(256)
void cvt_f32_bf16(const float* __restrict__ src, bf16* __restrict__ dst, int n) {
  int i = (blockIdx.x * 256 + threadIdx.x) * 4;
  if (i < n) {
    floatx4 f = *(const floatx4*)(src + i);
    short4v h;
    h[0] = f2b_bits(f[0]); h[1] = f2b_bits(f[1]);
    h[2] = f2b_bits(f[2]); h[3] = f2b_bits(f[3]);
    *(short4v*)(dst + i) = h;
  }
}

// ---------------------------------------------------------------------------
// GEMM core: C = A[M,K] * Bm[N,K]^T + bias, bf16 DMA staging, fp32 accum.
// EPI=1: C fp32 (final output). EPI=2: QKV split epilogue (Qp/Kp token-major,
// Vt transposed [b][h][d][t]).
// 128x128 tile, BK=64, 4 waves x (64x64) of 16x16x32 MFMA.
// R9 loop: dbuf slots, deep prefetch, counted vmcnt(8), raw barriers,
// T2 swizzle (source-side + read-side), T1 XCD block chunking.
// ---------------------------------------------------------------------------
template<int EPI>
__global__ __launch_bounds__(256)
void gemm_bt_bias(const bf16* __restrict__ A, const bf16* __restrict__ Bm,
                  const bf16* __restrict__ bias, void* __restrict__ C0,
                  void* __restrict__ C1, void* __restrict__ C2,
                  int M, int N, int K)
{
  __shared__ __align__(16) unsigned short sA[2][128 * 64];
  __shared__ __align__(16) unsigned short sB[2][128 * 64];

  const int tid  = threadIdx.x;
  const int lane = tid & 63;
  const int wv   = tid >> 6;
  const int quad = lane >> 4;
  const int l16  = lane & 15;
  const int wm   = wv >> 1, wn = wv & 1;

  // T1: XCD-chunked block swizzle. nwg % 8 == 0 for both launches (1536/512).
  const int gx   = gridDim.x;
  const int nwg  = gx * gridDim.y;
  const int bidl = blockIdx.y * gx + blockIdx.x;
  const int swzb = (bidl & 7) * (nwg >> 3) + (bidl >> 3);
  const int bn   = swzb % gx, bm = swzb / gx;

  floatx4 acc[4][4];
#pragma unroll
  for (int i = 0; i < 4; ++i)
#pragma unroll
    for (int j = 0; j < 4; ++j) acc[i][j] = (floatx4){0.f, 0.f, 0.f, 0.f};

  // staging geometry: thread covers LDS bytes o = it*4096 + wv*1024 + lane*16.
  // LDS dest stays LINEAR (gl2lds: wave base + lane*16). Global source is
  // pre-swizzled: col_byte = (o&127) ^ ((row&7)<<4)  (involution, rule #21).
  const int o_base = wv * 1024 + lane * 16;
  const bf16* gA[4];
  const bf16* gB[4];
#pragma unroll
  for (int it = 0; it < 4; ++it) {
    int o   = it * 4096 + o_base;
    int row = o >> 7;
    int col = ((o & 127) ^ ((row & 7) << 4)) >> 1;
    gA[it] = A  + (size_t)(bm * 128 + row) * K + col;
    gB[it] = Bm + (size_t)(bn * 128 + row) * K + col;
  }

  const int NT = K >> 6;
  // prologue: stage tile 0 -> slot 0
#pragma unroll
  for (int it = 0; it < 4; ++it)
    gl2lds16(gA[it], &sA[0][(it * 4096 + wv * 1024) >> 1]);
#pragma unroll
  for (int it = 0; it < 4; ++it)
    gl2lds16(gB[it], &sB[0][(it * 4096 + wv * 1024) >> 1]);

  const int swx = (l16 & 7) << 3;   // read-side element XOR (rows: row&7 == l16&7)

  for (int t = 0; t < NT; ++t) {
    const int s = t & 1;
    if (t + 1 < NT) {
      // stage tile t+1 -> slot s^1 (last read in compute(t-1), before barrier2)
#pragma unroll
      for (int it = 0; it < 4; ++it)
        gl2lds16(gA[it] + (size_t)(t + 1) * 64, &sA[s ^ 1][(it * 4096 + wv * 1024) >> 1]);
#pragma unroll
      for (int it = 0; it < 4; ++it)
        gl2lds16(gB[it] + (size_t)(t + 1) * 64, &sB[s ^ 1][(it * 4096 + wv * 1024) >> 1]);
      __builtin_amdgcn_sched_barrier(0);
      // outstanding = 8 (tile t) + 8 (tile t+1); wait the oldest 8 only.
      asm volatile("s_waitcnt vmcnt(8)" ::: "memory");
    } else {
      asm volatile("s_waitcnt vmcnt(0)" ::: "memory");
    }
    __builtin_amdgcn_s_barrier();        // barrier1: tile t visible to all
    __builtin_amdgcn_sched_barrier(0);

#pragma unroll
    for (int kk = 0; kk < 64; kk += 32) {
      short8 a_[4], b_[4];
#pragma unroll
      for (int i = 0; i < 4; ++i)
        a_[i] = *(const short8*)&sA[s][(wm * 64 + i * 16 + l16) * 64 + ((kk + quad * 8) ^ swx)];
#pragma unroll
      for (int j = 0; j < 4; ++j)
        b_[j] = *(const short8*)&sB[s][(wn * 64 + j * 16 + l16) * 64 + ((kk + quad * 8) ^ swx)];
#pragma unroll
      for (int i = 0; i < 4; ++i)
#pragma unroll
        for (int j = 0; j < 4; ++j)
          acc[i][j] = __builtin_amdgcn_mfma_f32_16x16x32_bf16(a_[i], b_[j], acc[i][j], 0, 0, 0);
    }

    __builtin_amdgcn_sched_barrier(0);
    __builtin_amdgcn_s_barrier();        // barrier2: all done reading slot s
  }

  if (EPI == 1) {
    // final projection: fp32 C0[M,N]
#pragma unroll
    for (int j = 0; j < 4; ++j) {
      const int colg = bn * 128 + wn * 64 + j * 16 + l16;
      const float bv = __bfloat162float(bias[colg]);
#pragma unroll
      for (int i = 0; i < 4; ++i)
#pragma unroll
        for (int r = 0; r < 4; ++r) {
          int rowg = bm * 128 + wm * 64 + i * 16 + quad * 4 + r;
          ((float*)C0)[(size_t)rowg * N + colg] = acc[i][j][r] + bv;
        }
    }
  } else {
    // QKV split: bn 0..7 -> Qp (C0), 8..15 -> Kp (C1), 16..23 -> Vt (C2)
    const int region = bn >> 3;
    if (region < 2) {
      bf16* dst = (bf16*)(region == 0 ? C0 : C1);
#pragma unroll
      for (int j = 0; j < 4; ++j) {
        const int colg = bn * 128 + wn * 64 + j * 16 + l16;        // 0..3071
        const int colr = colg & 1023;                              // col in region
        const float bv = __bfloat162float(bias[colg]);
#pragma unroll
        for (int i = 0; i < 4; ++i)
#pragma unroll
          for (int r = 0; r < 4; ++r) {
            int rowg = bm * 128 + wm * 64 + i * 16 + quad * 4 + r;
            dst[(size_t)rowg * 1024 + colr] = __float2bfloat16(acc[i][j][r] + bv);
          }
      }
    } else {
      // V transposed: Vt[(b*16+h)<<16 | d*1024 | t], r-packed b64 stores
      bf16* vt = (bf16*)C2;
#pragma unroll
      for (int j = 0; j < 4; ++j) {
        const int colg = bn * 128 + wn * 64 + j * 16 + l16;
        const int d  = colg & 63;
        const int hh = (colg >> 6) & 15;
        const float bv = __bfloat162float(bias[colg]);
#pragma unroll
        for (int i = 0; i < 4; ++i) {
          int rowg0 = bm * 128 + wm * 64 + i * 16 + quad * 4;
          int bb = rowg0 >> 10, t0 = rowg0 & 1023;
          short4v pk;
#pragma unroll
          for (int r = 0; r < 4; ++r) pk[r] = (short)f2b_bits(acc[i][j][r] + bv);
          *(short4v*)&vt[((size_t)(bb * 16 + hh) << 16) + ((size_t)d << 10) + t0] = pk;
        }
      }
    }
  }
}

// ---------------------------------------------------------------------------
// Fused attention. grid = (H, T/128, B), 512 threads (8 waves x 16 rows),
// LDS 36.0KB. Q fragments in registers (loop-invariant). K and V^T
// register-staged into stride-72 LDS (balanced banks), software-pipelined
// across kt. Each thread stages exactly one 16B chunk of sK and one of sVT.
// sigma(n)=(n&15)*4+(n>>4) on K rows => logical score col = l16*4+j:
// float4 adj/mask loads. p=exp2(clamp(fma(sacc, avc, off))) with
// avc = av*cjv (folded scale); pack via v_cvt_pk_bf16_f32 (RNE) pairs,
// b64 sP stores. L row-sums via ones-column MFMA accumulated across kt.
// ---------------------------------------------------------------------------
__global__ __launch_bounds__(512)
void attn_fused(const bf16* __restrict__ Qp, const bf16* __restrict__ Kp,
                const bf16* __restrict__ Vt, const float* __restrict__ adj,
                const float* __restrict__ mask, bf16* __restrict__ aout)
{
  __shared__ __align__(16) unsigned short sK[64 * 72];
  __shared__ __align__(16) unsigned short sVT[64 * 72];
  __shared__ __align__(16) unsigned short sP[128 * 72];

  const int tid  = threadIdx.x;
  const int lane = tid & 63;
  const int wv   = tid >> 6;          // 0..7
  const int quad = lane >> 4;
  const int l16  = lane & 15;
  const int h = blockIdx.x, qt = blockIdx.y, b = blockIdx.z;

  // Q fragments: rows qt*128 + wv*16 + l16, k = kk + quad*8 + [0..7]
  const bf16* qbase = Qp + (size_t)(b * T_ + qt * 128 + wv * 16 + l16) * 1024 + h * 64 + quad * 8;
  const short8 aq0 = *(const short8*)qbase;
  const short8 aq1 = *(const short8*)(qbase + 32);

  // staging: 512 threads cover 64 rows x 8 chunks, one 16B chunk each
  const int srow  = tid >> 3;                          // 0..63
  const int chunk = (tid & 7) * 8;
  const int sig = ((srow & 15) << 2) | (srow >> 4);    // token offset for sK row
  const bf16* kb = Kp + (size_t)(b * T_ + sig) * 1024 + h * 64 + chunk;  // +kt<<16
  const bf16* vb = Vt + ((size_t)(b * 16 + h) << 16) + ((size_t)srow << 10) + chunk; // +kt*64

  // adj/mask row pointers
  const float* mb = mask + b * T_ + l16 * 4;
  const float* adjr[4];
#pragma unroll
  for (int r = 0; r < 4; ++r)
    adjr[r] = adj + ((size_t)b * T_ + qt * 128 + wv * 16 + quad * 4 + r) * T_ + l16 * 4;

  // preload kt=0 staging registers
  short8 kr = *(const short8*)kb;
  short8 vr = *(const short8*)vb;

  // bf16 1.0 fragment for L row-sums via MFMA
  short8 ones8;
#pragma unroll
  for (int i = 0; i < 8; ++i) ones8[i] = (short)0x3F80;

  floatx4 oacc[4];
#pragma unroll
  for (int d = 0; d < 4; ++d) oacc[d] = (floatx4){0.f, 0.f, 0.f, 0.f};
  floatx4 Lacc = (floatx4){0.f, 0.f, 0.f, 0.f};

  const float SC = 0.125f * 1.44269504088896f;   // (1/sqrt(dh)) * log2(e)

  for (int kt = 0; kt < 16; ++kt) {
    // adj/mask for this tile (logical cols kt*64 + l16*4 + {0..3})
    floatx4 av[4];
    floatx4 mk4 = *(const floatx4*)(mb + kt * 64);
#pragma unroll
    for (int r = 0; r < 4; ++r) av[r] = *(const floatx4*)(adjr[r] + kt * 64);
    floatx4 cjv, offv;
#pragma unroll
    for (int j = 0; j < 4; ++j) {
      cjv[j]  = mk4[j] * SC;
      offv[j] = (mk4[j] == 0.f) ? -1e30f : 0.f;
    }

    __syncthreads();   // sync1: all waves done reading sK/sVT of prev kt
    *(short8*)&sK [srow * 72 + chunk] = kr;
    *(short8*)&sVT[srow * 72 + chunk] = vr;
    __syncthreads();   // sync2: staging visible

    // prefetch next kt's staging registers (VMEM overlaps compute below)
    {
      int nk = kt < 15 ? kt + 1 : 15;
      kr = *(const short8*)(kb + ((size_t)nk << 16));
      vr = *(const short8*)(vb + (nk << 6));
    }

    // S = Q K^T  (sacc[j][r]: row wv*16+quad*4+r, logical col l16*4+j)
    floatx4 sacc[4];
#pragma unroll
    for (int j = 0; j < 4; ++j) sacc[j] = (floatx4){0.f, 0.f, 0.f, 0.f};
    __builtin_amdgcn_s_setprio(1);
#pragma unroll
    for (int kk = 0; kk < 64; kk += 32) {
      short8 aq = kk ? aq1 : aq0;
#pragma unroll
      for (int j = 0; j < 4; ++j) {
        short8 bk = *(const short8*)&sK[(j * 16 + l16) * 72 + kk + quad * 8];
        sacc[j] = __builtin_amdgcn_mfma_f32_16x16x32_bf16(aq, bk, sacc[j], 0, 0, 0);
      }
    }
    __builtin_amdgcn_s_setprio(0);

    // p = exp2(clamp(fma(sacc, avc, off))); pack pairs via v_cvt_pk_bf16_f32
#pragma unroll
    for (int r = 0; r < 4; ++r) {
      floatx4 avc = av[r] * cjv;      // folded adj*mask*SC (pk-pairable)
      float p[4];
#pragma unroll
      for (int j = 0; j < 4; ++j) {
        float z = fminf(fmaf(sacc[j][r], avc[j], offv[j]), 100.f);
        p[j] = exp2f(z);
      }
      unsigned w0, w1;
      asm("v_cvt_pk_bf16_f32 %0, %1, %2" : "=v"(w0) : "v"(p[0]), "v"(p[1]));
      asm("v_cvt_pk_bf16_f32 %0, %1, %2" : "=v"(w1) : "v"(p[2]), "v"(p[3]));
      uint2v pw; pw[0] = w0; pw[1] = w1;
      *(uint2v*)&sP[(wv * 16 + quad * 4 + r) * 72 + l16 * 4] = pw;
    }

    // sP rows wave-local; same-wave DS is HW-ordered. Stop compiler reorder:
    __asm__ __volatile__("" ::: "memory");

    // O += P V ; L += P * ones
    __builtin_amdgcn_s_setprio(1);
#pragma unroll
    for (int kk = 0; kk < 64; kk += 32) {
      short8 ap = *(const short8*)&sP[(wv * 16 + l16) * 72 + kk + quad * 8];
      Lacc = __builtin_amdgcn_mfma_f32_16x16x32_bf16(ap, ones8, Lacc, 0, 0, 0);
#pragma unroll
      for (int d = 0; d < 4; ++d) {
        short8 bv = *(const short8*)&sVT[(d * 16 + l16) * 72 + kk + quad * 8];
        oacc[d] = __builtin_amdgcn_mfma_f32_16x16x32_bf16(ap, bv, oacc[d], 0, 0, 0);
      }
    }
    __builtin_amdgcn_s_setprio(0);
  }

  // epilogue: Lacc[r] already holds the full row sum (every col identical)
#pragma unroll
  for (int d = 0; d < 4; ++d) {
#pragma unroll
    for (int r = 0; r < 4; ++r) {
      int qrow = qt * 128 + wv * 16 + quad * 4 + r;
      float val = oacc[d][r] / (Lacc[r] + 1e-13f);
      aout[(size_t)(b * T_ + qrow) * 1024 + h * 64 + d * 16 + l16] = __float2bfloat16(val);
    }
  }
}

// ---------------------------------------------------------------------------
extern "C" void kernel_launch(void* const* d_in, const int* in_sizes, int n_in,
                              void* d_out, int out_size, void* d_ws, size_t ws_size,
                              hipStream_t stream) {
  const float* inputs = (const float*)d_in[0];   // [8,1024,1024]
  const float* mask   = (const float*)d_in[1];   // [8,1024]
  const float* adj    = (const float*)d_in[2];   // [8,1024,1024]
  const float* W_qkv  = (const float*)d_in[3];   // [3072,1024]
  const float* b_qkv  = (const float*)d_in[4];   // [3072]
  const float* W_out  = (const float*)d_in[5];   // [1024,1024]
  const float* b_out  = (const float*)d_in[6];   // [1024]

  const size_t SEG = (size_t)8192 * 1024;        // 16 MiB bf16 segments
  bf16* Qp   = (bf16*)d_ws;                      // @0
  bf16* Kp   = Qp + SEG;                         // @16MiB
  bf16* Vt   = Kp + SEG;                         // @32MiB
  bf16* aout = Vt + SEG;                         // @48MiB
  bf16* wo_bf = Qp;                              // Qp dead after attn
  bf16* bo_bf = Qp + (size_t)1024 * 1024;

  // d_out as phase-1 scratch (32MiB fp32 region, dead until GEMM3)
  bf16* ib_bf = (bf16*)d_out;                    // 16MiB
  bf16* wq_bf = ib_bf + SEG;                     // 6MiB
  bf16* bq_bf = wq_bf + (size_t)3072 * 1024;

  dim3 blk(256);
  cvt_f32_bf16<<<dim3(8192 * 1024 / 4 / 256), blk, 0, stream>>>(inputs, ib_bf, 8192 * 1024);
  cvt_f32_bf16<<<dim3(3072 * 1024 / 4 / 256), blk, 0, stream>>>(W_qkv, wq_bf, 3072 * 1024);
  cvt_f32_bf16<<<dim3(3), blk, 0, stream>>>(b_qkv, bq_bf, 3072);
  // QKV projection with split epilogue (Qp, Kp, Vt)
  gemm_bt_bias<2><<<dim3(PROJW / 128, (B_ * T_) / 128), blk, 0, stream>>>(
      ib_bf, wq_bf, bq_bf, Qp, Kp, Vt, B_ * T_, PROJW, D_);
  // fused attention (512 threads, 128 q-rows/block)
  attn_fused<<<dim3(H_, T_ / 128, B_), dim3(512), 0, stream>>>(Qp, Kp, Vt, adj, mask, aout);
  // output projection weights into dead Qp region
  cvt_f32_bf16<<<dim3(1024 * 1024 / 4 / 256), blk, 0, stream>>>(W_out, wo_bf, 1024 * 1024);
  cvt_f32_bf16<<<dim3(1), blk, 0, stream>>>(b_out, bo_bf, 1024);
  // output projection: C fp32 -> d_out
  gemm_bt_bias<1><<<dim3(D_ / 128, (B_ * T_) / 128), blk, 0, stream>>>(
      aout, wo_bf, bo_bf, d_out, nullptr, nullptr, B_ * T_, D_, D_);
}

// Round 4
// 274.619 us; speedup vs baseline: 1.1476x; 1.0371x over previous
//
#include <hip/hip_runtime.h>
#include <hip/hip_bf16.h>
#include <cstdint>

// ============================================================================
// MultiHeadSelfAttention: B=8 T=1024 D=1024 H=16 dh=64. fp32 in / fp32 out.
// R11: attn hidden-VALU cut + L2 locality (R10 post-mortem: cvt_pk barely
// moved VALUBusy; accounting shows ~950 VALU-cyc/wave-kt vs ~300 visible ->
// exp2f is an OCML call (~10-15 VALU each, 16/kt/lane), not v_exp_f32):
//  - fast_exp2: __builtin_amdgcn_exp2f (raw v_exp_f32) w/ asm fallback.
//    Input already clamped to [-1e30, 100]; v_exp(-1e30)=0 exact.
//  - attn work swizzle: bid=(h+16qt+128b); assign b=bid&7 (=XCD),
//    h=(bid>>3)&15 fastest, qt=bid>>7. 16 consecutive same-XCD blocks share
//    the 512KB adj slice (was spread over 8 XCDs -> ~5x adj refetch);
//    K/V[b] stays XCD-local too. Bijective remap, perf-only.
//  GEMMs, staging, barriers, epilogues identical to R10.
// R9/R10 recap: GEMM dbuf + counted vmcnt(8) + raw barriers + T2 both-sides
// swizzle + T1 XCD chunking; attn 512thr/128 q-rows, ones-MFMA L, setprio,
// cvt_pk_bf16 P-pack, folded scale.
// ws (64MiB): Qp@0, Kp@16MiB, Vt@32MiB, aout@48MiB (each [8192][1024] bf16).
// d_out scratch phase 1: ib_bf@0 (16MiB), wq_bf@16MiB (6MiB), bq_bf@22MiB.
// After attn: wo_bf/bo_bf overwrite dead Qp@0. GEMM3 writes d_out fp32 last.
// ============================================================================

using bf16 = __hip_bfloat16;
typedef __attribute__((ext_vector_type(8))) short short8;
typedef __attribute__((ext_vector_type(4))) short short4v;
typedef __attribute__((ext_vector_type(4))) float floatx4;
typedef __attribute__((ext_vector_type(2))) unsigned int uint2v;

#define B_    8
#define T_    1024
#define D_    1024
#define H_    16
#define PROJW 3072

__device__ __forceinline__ void gl2lds16(const void* g, void* l) {
  __builtin_amdgcn_global_load_lds(
      (const __attribute__((address_space(1))) void*)g,
      (__attribute__((address_space(3))) void*)l,
      16, 0, 0);
}

__device__ __forceinline__ unsigned short f2b_bits(float f) {
  return __builtin_bit_cast(unsigned short, __float2bfloat16(f));
}

// raw v_exp_f32 (1 ulp), bypassing the OCML exp2f range-fixup path
__device__ __forceinline__ float fast_exp2(float x) {
#if __has_builtin(__builtin_amdgcn_exp2f)
  return __builtin_amdgcn_exp2f(x);
#else
  float r;
  asm("v_exp_f32 %0, %1\ns_nop 0" : "=v"(r) : "v"(x));
  return r;
#endif
}

// ---------------------------------------------------------------------------
// fp32 -> bf16 elementwise convert (n multiple of 4), RNE
// ---------------------------------------------------------------------------
__global__ __launch_bounds__(256)
void cvt_f32_bf16(const float* __restrict__ src, bf16* __restrict__ dst, int n) {
  int i = (blockIdx.x * 256 + threadIdx.x) * 4;
  if (i < n) {
    floatx4 f = *(const floatx4*)(src + i);
    short4v h;
    h[0] = f2b_bits(f[0]); h[1] = f2b_bits(f[1]);
    h[2] = f2b_bits(f[2]); h[3] = f2b_bits(f[3]);
    *(short4v*)(dst + i) = h;
  }
}

// ---------------------------------------------------------------------------
// GEMM core: C = A[M,K] * Bm[N,K]^T + bias, bf16 DMA staging, fp32 accum.
// EPI=1: C fp32 (final output). EPI=2: QKV split epilogue (Qp/Kp token-major,
// Vt transposed [b][h][d][t]).
// 128x128 tile, BK=64, 4 waves x (64x64) of 16x16x32 MFMA.
// R9 loop: dbuf slots, deep prefetch, counted vmcnt(8), raw barriers,
// T2 swizzle (source-side + read-side), T1 XCD block chunking.
// ---------------------------------------------------------------------------
template<int EPI>
__global__ __launch_bounds__(256)
void gemm_bt_bias(const bf16* __restrict__ A, const bf16* __restrict__ Bm,
                  const bf16* __restrict__ bias, void* __restrict__ C0,
                  void* __restrict__ C1, void* __restrict__ C2,
                  int M, int N, int K)
{
  __shared__ __align__(16) unsigned short sA[2][128 * 64];
  __shared__ __align__(16) unsigned short sB[2][128 * 64];

  const int tid  = threadIdx.x;
  const int lane = tid & 63;
  const int wv   = tid >> 6;
  const int quad = lane >> 4;
  const int l16  = lane & 15;
  const int wm   = wv >> 1, wn = wv & 1;

  // T1: XCD-chunked block swizzle. nwg % 8 == 0 for both launches (1536/512).
  const int gx   = gridDim.x;
  const int nwg  = gx * gridDim.y;
  const int bidl = blockIdx.y * gx + blockIdx.x;
  const int swzb = (bidl & 7) * (nwg >> 3) + (bidl >> 3);
  const int bn   = swzb % gx, bm = swzb / gx;

  floatx4 acc[4][4];
#pragma unroll
  for (int i = 0; i < 4; ++i)
#pragma unroll
    for (int j = 0; j < 4; ++j) acc[i][j] = (floatx4){0.f, 0.f, 0.f, 0.f};

  // staging geometry: thread covers LDS bytes o = it*4096 + wv*1024 + lane*16.
  // LDS dest stays LINEAR (gl2lds: wave base + lane*16). Global source is
  // pre-swizzled: col_byte = (o&127) ^ ((row&7)<<4)  (involution, rule #21).
  const int o_base = wv * 1024 + lane * 16;
  const bf16* gA[4];
  const bf16* gB[4];
#pragma unroll
  for (int it = 0; it < 4; ++it) {
    int o   = it * 4096 + o_base;
    int row = o >> 7;
    int col = ((o & 127) ^ ((row & 7) << 4)) >> 1;
    gA[it] = A  + (size_t)(bm * 128 + row) * K + col;
    gB[it] = Bm + (size_t)(bn * 128 + row) * K + col;
  }

  const int NT = K >> 6;
  // prologue: stage tile 0 -> slot 0
#pragma unroll
  for (int it = 0; it < 4; ++it)
    gl2lds16(gA[it], &sA[0][(it * 4096 + wv * 1024) >> 1]);
#pragma unroll
  for (int it = 0; it < 4; ++it)
    gl2lds16(gB[it], &sB[0][(it * 4096 + wv * 1024) >> 1]);

  const int swx = (l16 & 7) << 3;   // read-side element XOR (rows: row&7 == l16&7)

  for (int t = 0; t < NT; ++t) {
    const int s = t & 1;
    if (t + 1 < NT) {
      // stage tile t+1 -> slot s^1 (last read in compute(t-1), before barrier2)
#pragma unroll
      for (int it = 0; it < 4; ++it)
        gl2lds16(gA[it] + (size_t)(t + 1) * 64, &sA[s ^ 1][(it * 4096 + wv * 1024) >> 1]);
#pragma unroll
      for (int it = 0; it < 4; ++it)
        gl2lds16(gB[it] + (size_t)(t + 1) * 64, &sB[s ^ 1][(it * 4096 + wv * 1024) >> 1]);
      __builtin_amdgcn_sched_barrier(0);
      // outstanding = 8 (tile t) + 8 (tile t+1); wait the oldest 8 only.
      asm volatile("s_waitcnt vmcnt(8)" ::: "memory");
    } else {
      asm volatile("s_waitcnt vmcnt(0)" ::: "memory");
    }
    __builtin_amdgcn_s_barrier();        // barrier1: tile t visible to all
    __builtin_amdgcn_sched_barrier(0);

#pragma unroll
    for (int kk = 0; kk < 64; kk += 32) {
      short8 a_[4], b_[4];
#pragma unroll
      for (int i = 0; i < 4; ++i)
        a_[i] = *(const short8*)&sA[s][(wm * 64 + i * 16 + l16) * 64 + ((kk + quad * 8) ^ swx)];
#pragma unroll
      for (int j = 0; j < 4; ++j)
        b_[j] = *(const short8*)&sB[s][(wn * 64 + j * 16 + l16) * 64 + ((kk + quad * 8) ^ swx)];
#pragma unroll
      for (int i = 0; i < 4; ++i)
#pragma unroll
        for (int j = 0; j < 4; ++j)
          acc[i][j] = __builtin_amdgcn_mfma_f32_16x16x32_bf16(a_[i], b_[j], acc[i][j], 0, 0, 0);
    }

    __builtin_amdgcn_sched_barrier(0);
    __builtin_amdgcn_s_barrier();        // barrier2: all done reading slot s
  }

  if (EPI == 1) {
    // final projection: fp32 C0[M,N]
#pragma unroll
    for (int j = 0; j < 4; ++j) {
      const int colg = bn * 128 + wn * 64 + j * 16 + l16;
      const float bv = __bfloat162float(bias[colg]);
#pragma unroll
      for (int i = 0; i < 4; ++i)
#pragma unroll
        for (int r = 0; r < 4; ++r) {
          int rowg = bm * 128 + wm * 64 + i * 16 + quad * 4 + r;
          ((float*)C0)[(size_t)rowg * N + colg] = acc[i][j][r] + bv;
        }
    }
  } else {
    // QKV split: bn 0..7 -> Qp (C0), 8..15 -> Kp (C1), 16..23 -> Vt (C2)
    const int region = bn >> 3;
    if (region < 2) {
      bf16* dst = (bf16*)(region == 0 ? C0 : C1);
#pragma unroll
      for (int j = 0; j < 4; ++j) {
        const int colg = bn * 128 + wn * 64 + j * 16 + l16;        // 0..3071
        const int colr = colg & 1023;                              // col in region
        const float bv = __bfloat162float(bias[colg]);
#pragma unroll
        for (int i = 0; i < 4; ++i)
#pragma unroll
          for (int r = 0; r < 4; ++r) {
            int rowg = bm * 128 + wm * 64 + i * 16 + quad * 4 + r;
            dst[(size_t)rowg * 1024 + colr] = __float2bfloat16(acc[i][j][r] + bv);
          }
      }
    } else {
      // V transposed: Vt[(b*16+h)<<16 | d*1024 | t], r-packed b64 stores
      bf16* vt = (bf16*)C2;
#pragma unroll
      for (int j = 0; j < 4; ++j) {
        const int colg = bn * 128 + wn * 64 + j * 16 + l16;
        const int d  = colg & 63;
        const int hh = (colg >> 6) & 15;
        const float bv = __bfloat162float(bias[colg]);
#pragma unroll
        for (int i = 0; i < 4; ++i) {
          int rowg0 = bm * 128 + wm * 64 + i * 16 + quad * 4;
          int bb = rowg0 >> 10, t0 = rowg0 & 1023;
          short4v pk;
#pragma unroll
          for (int r = 0; r < 4; ++r) pk[r] = (short)f2b_bits(acc[i][j][r] + bv);
          *(short4v*)&vt[((size_t)(bb * 16 + hh) << 16) + ((size_t)d << 10) + t0] = pk;
        }
      }
    }
  }
}

// ---------------------------------------------------------------------------
// Fused attention. grid = (16, 8, 8), 512 threads (8 waves x 16 rows),
// LDS 36.0KB. Work swizzle: bid -> b=bid&7 (XCD), h=(bid>>3)&15 (fastest,
// adj-sharing blocks contiguous on one XCD), qt=bid>>7.
// Q fragments in registers (loop-invariant). K and V^T register-staged into
// stride-72 LDS (balanced banks), software-pipelined across kt.
// sigma(n)=(n&15)*4+(n>>4) on K rows => logical score col = l16*4+j:
// float4 adj/mask loads. p=fast_exp2(clamp(fma(sacc, avc, off))) with
// avc = av*cjv (folded scale); pack via v_cvt_pk_bf16_f32 (RNE) pairs,
// b64 sP stores. L row-sums via ones-column MFMA accumulated across kt.
// ---------------------------------------------------------------------------
__global__ __launch_bounds__(512)
void attn_fused(const bf16* __restrict__ Qp, const bf16* __restrict__ Kp,
                const bf16* __restrict__ Vt, const float* __restrict__ adj,
                const float* __restrict__ mask, bf16* __restrict__ aout)
{
  __shared__ __align__(16) unsigned short sK[64 * 72];
  __shared__ __align__(16) unsigned short sVT[64 * 72];
  __shared__ __align__(16) unsigned short sP[128 * 72];

  const int tid  = threadIdx.x;
  const int lane = tid & 63;
  const int wv   = tid >> 6;          // 0..7
  const int quad = lane >> 4;
  const int l16  = lane & 15;

  // work swizzle: adj-sharing (b,qt) groups contiguous per XCD, K/V[b] local
  const int bid  = blockIdx.x + 16 * (blockIdx.y + 8 * blockIdx.z);
  const int b    = bid & 7;
  const int slot = bid >> 3;
  const int h    = slot & 15;
  const int qt   = slot >> 4;

  // Q fragments: rows qt*128 + wv*16 + l16, k = kk + quad*8 + [0..7]
  const bf16* qbase = Qp + (size_t)(b * T_ + qt * 128 + wv * 16 + l16) * 1024 + h * 64 + quad * 8;
  const short8 aq0 = *(const short8*)qbase;
  const short8 aq1 = *(const short8*)(qbase + 32);

  // staging: 512 threads cover 64 rows x 8 chunks, one 16B chunk each
  const int srow  = tid >> 3;                          // 0..63
  const int chunk = (tid & 7) * 8;
  const int sig = ((srow & 15) << 2) | (srow >> 4);    // token offset for sK row
  const bf16* kb = Kp + (size_t)(b * T_ + sig) * 1024 + h * 64 + chunk;  // +kt<<16
  const bf16* vb = Vt + ((size_t)(b * 16 + h) << 16) + ((size_t)srow << 10) + chunk; // +kt*64

  // adj/mask row pointers
  const float* mb = mask + b * T_ + l16 * 4;
  const float* adjr[4];
#pragma unroll
  for (int r = 0; r < 4; ++r)
    adjr[r] = adj + ((size_t)b * T_ + qt * 128 + wv * 16 + quad * 4 + r) * T_ + l16 * 4;

  // preload kt=0 staging registers
  short8 kr = *(const short8*)kb;
  short8 vr = *(const short8*)vb;

  // bf16 1.0 fragment for L row-sums via MFMA
  short8 ones8;
#pragma unroll
  for (int i = 0; i < 8; ++i) ones8[i] = (short)0x3F80;

  floatx4 oacc[4];
#pragma unroll
  for (int d = 0; d < 4; ++d) oacc[d] = (floatx4){0.f, 0.f, 0.f, 0.f};
  floatx4 Lacc = (floatx4){0.f, 0.f, 0.f, 0.f};

  const float SC = 0.125f * 1.44269504088896f;   // (1/sqrt(dh)) * log2(e)

  for (int kt = 0; kt < 16; ++kt) {
    // adj/mask for this tile (logical cols kt*64 + l16*4 + {0..3})
    floatx4 av[4];
    floatx4 mk4 = *(const floatx4*)(mb + kt * 64);
#pragma unroll
    for (int r = 0; r < 4; ++r) av[r] = *(const floatx4*)(adjr[r] + kt * 64);
    floatx4 cjv, offv;
#pragma unroll
    for (int j = 0; j < 4; ++j) {
      cjv[j]  = mk4[j] * SC;
      offv[j] = (mk4[j] == 0.f) ? -1e30f : 0.f;
    }

    __syncthreads();   // sync1: all waves done reading sK/sVT of prev kt
    *(short8*)&sK [srow * 72 + chunk] = kr;
    *(short8*)&sVT[srow * 72 + chunk] = vr;
    __syncthreads();   // sync2: staging visible

    // prefetch next kt's staging registers (VMEM overlaps compute below)
    {
      int nk = kt < 15 ? kt + 1 : 15;
      kr = *(const short8*)(kb + ((size_t)nk << 16));
      vr = *(const short8*)(vb + (nk << 6));
    }

    // S = Q K^T  (sacc[j][r]: row wv*16+quad*4+r, logical col l16*4+j)
    floatx4 sacc[4];
#pragma unroll
    for (int j = 0; j < 4; ++j) sacc[j] = (floatx4){0.f, 0.f, 0.f, 0.f};
    __builtin_amdgcn_s_setprio(1);
#pragma unroll
    for (int kk = 0; kk < 64; kk += 32) {
      short8 aq = kk ? aq1 : aq0;
#pragma unroll
      for (int j = 0; j < 4; ++j) {
        short8 bk = *(const short8*)&sK[(j * 16 + l16) * 72 + kk + quad * 8];
        sacc[j] = __builtin_amdgcn_mfma_f32_16x16x32_bf16(aq, bk, sacc[j], 0, 0, 0);
      }
    }
    __builtin_amdgcn_s_setprio(0);

    // p = fast_exp2(clamp(fma(sacc, avc, off))); pack via v_cvt_pk_bf16_f32
#pragma unroll
    for (int r = 0; r < 4; ++r) {
      floatx4 avc = av[r] * cjv;      // folded adj*mask*SC (pk-pairable)
      float p[4];
#pragma unroll
      for (int j = 0; j < 4; ++j) {
        float z = fminf(fmaf(sacc[j][r], avc[j], offv[j]), 100.f);
        p[j] = fast_exp2(z);
      }
      unsigned w0, w1;
      asm("v_cvt_pk_bf16_f32 %0, %1, %2" : "=v"(w0) : "v"(p[0]), "v"(p[1]));
      asm("v_cvt_pk_bf16_f32 %0, %1, %2" : "=v"(w1) : "v"(p[2]), "v"(p[3]));
      uint2v pw; pw[0] = w0; pw[1] = w1;
      *(uint2v*)&sP[(wv * 16 + quad * 4 + r) * 72 + l16 * 4] = pw;
    }

    // sP rows wave-local; same-wave DS is HW-ordered. Stop compiler reorder:
    __asm__ __volatile__("" ::: "memory");

    // O += P V ; L += P * ones
    __builtin_amdgcn_s_setprio(1);
#pragma unroll
    for (int kk = 0; kk < 64; kk += 32) {
      short8 ap = *(const short8*)&sP[(wv * 16 + l16) * 72 + kk + quad * 8];
      Lacc = __builtin_amdgcn_mfma_f32_16x16x32_bf16(ap, ones8, Lacc, 0, 0, 0);
#pragma unroll
      for (int d = 0; d < 4; ++d) {
        short8 bv = *(const short8*)&sVT[(d * 16 + l16) * 72 + kk + quad * 8];
        oacc[d] = __builtin_amdgcn_mfma_f32_16x16x32_bf16(ap, bv, oacc[d], 0, 0, 0);
      }
    }
    __builtin_amdgcn_s_setprio(0);
  }

  // epilogue: Lacc[r] already holds the full row sum (every col identical)
#pragma unroll
  for (int d = 0; d < 4; ++d) {
#pragma unroll
    for (int r = 0; r < 4; ++r) {
      int qrow = qt * 128 + wv * 16 + quad * 4 + r;
      float val = oacc[d][r] / (Lacc[r] + 1e-13f);
      aout[(size_t)(b * T_ + qrow) * 1024 + h * 64 + d * 16 + l16] = __float2bfloat16(val);
    }
  }
}

// ---------------------------------------------------------------------------
extern "C" void kernel_launch(void* const* d_in, const int* in_sizes, int n_in,
                              void* d_out, int out_size, void* d_ws, size_t ws_size,
                              hipStream_t stream) {
  const float* inputs = (const float*)d_in[0];   // [8,1024,1024]
  const float* mask   = (const float*)d_in[1];   // [8,1024]
  const float* adj    = (const float*)d_in[2];   // [8,1024,1024]
  const float* W_qkv  = (const float*)d_in[3];   // [3072,1024]
  const float* b_qkv  = (const float*)d_in[4];   // [3072]
  const float* W_out  = (const float*)d_in[5];   // [1024,1024]
  const float* b_out  = (const float*)d_in[6];   // [1024]

  const size_t SEG = (size_t)8192 * 1024;        // 16 MiB bf16 segments
  bf16* Qp   = (bf16*)d_ws;                      // @0
  bf16* Kp   = Qp + SEG;                         // @16MiB
  bf16* Vt   = Kp + SEG;                         // @32MiB
  bf16* aout = Vt + SEG;                         // @48MiB
  bf16* wo_bf = Qp;                              // Qp dead after attn
  bf16* bo_bf = Qp + (size_t)1024 * 1024;

  // d_out as phase-1 scratch (32MiB fp32 region, dead until GEMM3)
  bf16* ib_bf = (bf16*)d_out;                    // 16MiB
  bf16* wq_bf = ib_bf + SEG;                     // 6MiB
  bf16* bq_bf = wq_bf + (size_t)3072 * 1024;

  dim3 blk(256);
  cvt_f32_bf16<<<dim3(8192 * 1024 / 4 / 256), blk, 0, stream>>>(inputs, ib_bf, 8192 * 1024);
  cvt_f32_bf16<<<dim3(3072 * 1024 / 4 / 256), blk, 0, stream>>>(W_qkv, wq_bf, 3072 * 1024);
  cvt_f32_bf16<<<dim3(3), blk, 0, stream>>>(b_qkv, bq_bf, 3072);
  // QKV projection with split epilogue (Qp, Kp, Vt)
  gemm_bt_bias<2><<<dim3(PROJW / 128, (B_ * T_) / 128), blk, 0, stream>>>(
      ib_bf, wq_bf, bq_bf, Qp, Kp, Vt, B_ * T_, PROJW, D_);
  // fused attention (512 threads, 128 q-rows/block)
  attn_fused<<<dim3(H_, T_ / 128, B_), dim3(512), 0, stream>>>(Qp, Kp, Vt, adj, mask, aout);
  // output projection weights into dead Qp region
  cvt_f32_bf16<<<dim3(1024 * 1024 / 4 / 256), blk, 0, stream>>>(W_out, wo_bf, 1024 * 1024);
  cvt_f32_bf16<<<dim3(1), blk, 0, stream>>>(b_out, bo_bf, 1024);
  // output projection: C fp32 -> d_out
  gemm_bt_bias<1><<<dim3(D_ / 128, (B_ * T_) / 128), blk, 0, stream>>>(
      aout, wo_bf, bo_bf, d_out, nullptr, nullptr, B_ * T_, D_, D_);
}

// Round 6
// 272.674 us; speedup vs baseline: 1.1558x; 1.0071x over previous
//
#include <hip/hip_runtime.h>
#include <hip/hip_bf16.h>
#include <cstdint>

// ============================================================================
// MultiHeadSelfAttention: B=8 T=1024 D=1024 H=16 dh=64. fp32 in / fp32 out.
// R13 = R12 resubmit (R12 bench died to a container-infra failure, no
// counters; kernel audit found no hang/OOB risk: uniform barrier count,
// sound vmcnt ledger, bijective traversal, in-bounds epilogues).
// R12: GEMM latency-hiding (R11 counters: GEMM1 81us/636TF, MfmaUtil 26%,
// VALUBusy 20%, Occ 20%, conflicts 0 -> latency-bound on L3 B-fragment
// loads with only 8 waves/CU; FETCH 84MB vs 22MB ideal = L2 thrash from
// bn-fastest traversal streaming the 6MB W-panel per bm-row):
//  - 8-wave (512-thread) GEMM blocks, same 128x128 tile; wave tile 32x64,
//    acc[2][4]. Same grid/LDS/MFMA count; 16 waves/CU (4/SIMD) for TLP.
//    vmcnt ledger: 4 loads/wave/tile, 8 in flight -> s_waitcnt vmcnt(4).
//  - L2-aware traversal per XCD chunk (BNB=4): B-block 1MB L2-resident,
//    A panels streamed; L2 fill ~50MB -> ~18MB per XCD.
//  attn identical to R11.
// R9-R11 recap: GEMM dbuf + counted vmcnt + raw barriers + T2 both-sides
// swizzle; attn 512thr/128 q-rows, ones-MFMA L, setprio, cvt_pk P-pack,
// fast_exp2, b=XCD work swizzle.
// ws (64MiB): Qp@0, Kp@16MiB, Vt@32MiB, aout@48MiB (each [8192][1024] bf16).
// d_out scratch phase 1: ib_bf@0 (16MiB), wq_bf@16MiB (6MiB), bq_bf@22MiB.
// After attn: wo_bf/bo_bf overwrite dead Qp@0. GEMM3 writes d_out fp32 last.
// ============================================================================

using bf16 = __hip_bfloat16;
typedef __attribute__((ext_vector_type(8))) short short8;
typedef __attribute__((ext_vector_type(4))) short short4v;
typedef __attribute__((ext_vector_type(4))) float floatx4;
typedef __attribute__((ext_vector_type(2))) unsigned int uint2v;

#define B_    8
#define T_    1024
#define D_    1024
#define H_    16
#define PROJW 3072

__device__ __forceinline__ void gl2lds16(const void* g, void* l) {
  __builtin_amdgcn_global_load_lds(
      (const __attribute__((address_space(1))) void*)g,
      (__attribute__((address_space(3))) void*)l,
      16, 0, 0);
}

__device__ __forceinline__ unsigned short f2b_bits(float f) {
  return __builtin_bit_cast(unsigned short, __float2bfloat16(f));
}

// raw v_exp_f32 (1 ulp), bypassing the OCML exp2f range-fixup path
__device__ __forceinline__ float fast_exp2(float x) {
#if __has_builtin(__builtin_amdgcn_exp2f)
  return __builtin_amdgcn_exp2f(x);
#else
  float r;
  asm("v_exp_f32 %0, %1\ns_nop 0" : "=v"(r) : "v"(x));
  return r;
#endif
}

// ---------------------------------------------------------------------------
// fp32 -> bf16 elementwise convert (n multiple of 4), RNE
// ---------------------------------------------------------------------------
__global__ __launch_bounds__(256)
void cvt_f32_bf16(const float* __restrict__ src, bf16* __restrict__ dst, int n) {
  int i = (blockIdx.x * 256 + threadIdx.x) * 4;
  if (i < n) {
    floatx4 f = *(const floatx4*)(src + i);
    short4v h;
    h[0] = f2b_bits(f[0]); h[1] = f2b_bits(f[1]);
    h[2] = f2b_bits(f[2]); h[3] = f2b_bits(f[3]);
    *(short4v*)(dst + i) = h;
  }
}

// ---------------------------------------------------------------------------
// GEMM core: C = A[M,K] * Bm[N,K]^T + bias, bf16 DMA staging, fp32 accum.
// EPI=1: C fp32 (final output). EPI=2: QKV split epilogue (Qp/Kp token-major,
// Vt transposed [b][h][d][t]).
// 128x128 tile, BK=64, 512 threads: 8 waves x (32x64) of 16x16x32 MFMA.
// dbuf slots, deep prefetch, counted vmcnt(4), raw barriers, T2 swizzle
// (source-side + read-side), L2-aware XCD-chunk traversal (BNB=4).
// ---------------------------------------------------------------------------
template<int EPI>
__global__ __launch_bounds__(512)
void gemm_bt_bias(const bf16* __restrict__ A, const bf16* __restrict__ Bm,
                  const bf16* __restrict__ bias, void* __restrict__ C0,
                  void* __restrict__ C1, void* __restrict__ C2,
                  int M, int N, int K)
{
  __shared__ __align__(16) unsigned short sA[2][128 * 64];
  __shared__ __align__(16) unsigned short sB[2][128 * 64];

  const int tid  = threadIdx.x;
  const int lane = tid & 63;
  const int wv   = tid >> 6;          // 0..7
  const int quad = lane >> 4;
  const int l16  = lane & 15;
  const int wm   = wv >> 1;           // 0..3: 32-row band
  const int wn   = wv & 1;            // 0..1: 64-col band

  // L2-aware XCD-chunked traversal. Requires nwg%8==0, cpx%gx==0, gx%4==0
  // (GEMM1: nwg=1536 gx=24; GEMM3: nwg=512 gx=8).
  // XCD r owns linear ids with bidl&7==r (round-robin dispatch). Within the
  // chunk: bn-blocks of 4 (1MB B, L2-resident) over R bm panels (A streamed).
  const int gx   = gridDim.x;
  const int nwg  = gx * gridDim.y;
  const int bidl = blockIdx.y * gx + blockIdx.x;
  const int xcd  = bidl & 7;
  const int c    = bidl >> 3;
  const int cpx  = nwg >> 3;
  const int R    = cpx / gx;          // bm rows per XCD
  const int nb   = c / (R * 4);
  const int rem  = c % (R * 4);
  const int bm   = xcd * R + (rem >> 2);
  const int bn   = nb * 4 + (rem & 3);

  floatx4 acc[2][4];
#pragma unroll
  for (int i = 0; i < 2; ++i)
#pragma unroll
    for (int j = 0; j < 4; ++j) acc[i][j] = (floatx4){0.f, 0.f, 0.f, 0.f};

  // staging geometry: thread covers LDS bytes o = it*8192 + wv*1024 + lane*16,
  // it in {0,1} (512 threads x 16B x 2 = 16KB tile). LDS dest LINEAR; global
  // source pre-swizzled: col_byte = (o&127) ^ ((row&7)<<4) (rule #21).
  const int o_base = wv * 1024 + lane * 16;
  const bf16* gA[2];
  const bf16* gB[2];
#pragma unroll
  for (int it = 0; it < 2; ++it) {
    int o   = it * 8192 + o_base;
    int row = o >> 7;
    int col = ((o & 127) ^ ((row & 7) << 4)) >> 1;
    gA[it] = A  + (size_t)(bm * 128 + row) * K + col;
    gB[it] = Bm + (size_t)(bn * 128 + row) * K + col;
  }

  const int NT = K >> 6;
  // prologue: stage tile 0 -> slot 0 (4 loads/wave)
#pragma unroll
  for (int it = 0; it < 2; ++it)
    gl2lds16(gA[it], &sA[0][(it * 8192 + wv * 1024) >> 1]);
#pragma unroll
  for (int it = 0; it < 2; ++it)
    gl2lds16(gB[it], &sB[0][(it * 8192 + wv * 1024) >> 1]);

  const int swx = (l16 & 7) << 3;   // read-side element XOR (rows: row&7 == l16&7)

  for (int t = 0; t < NT; ++t) {
    const int s = t & 1;
    if (t + 1 < NT) {
      // stage tile t+1 -> slot s^1 (last read in compute(t-1), before barrier2)
#pragma unroll
      for (int it = 0; it < 2; ++it)
        gl2lds16(gA[it] + (size_t)(t + 1) * 64, &sA[s ^ 1][(it * 8192 + wv * 1024) >> 1]);
#pragma unroll
      for (int it = 0; it < 2; ++it)
        gl2lds16(gB[it] + (size_t)(t + 1) * 64, &sB[s ^ 1][(it * 8192 + wv * 1024) >> 1]);
      __builtin_amdgcn_sched_barrier(0);
      // outstanding = 4 (tile t) + 4 (tile t+1); wait the oldest 4 only.
      asm volatile("s_waitcnt vmcnt(4)" ::: "memory");
    } else {
      asm volatile("s_waitcnt vmcnt(0)" ::: "memory");
    }
    __builtin_amdgcn_s_barrier();        // barrier1: tile t visible to all
    __builtin_amdgcn_sched_barrier(0);

#pragma unroll
    for (int kk = 0; kk < 64; kk += 32) {
      short8 a_[2], b_[4];
#pragma unroll
      for (int i = 0; i < 2; ++i)
        a_[i] = *(const short8*)&sA[s][(wm * 32 + i * 16 + l16) * 64 + ((kk + quad * 8) ^ swx)];
#pragma unroll
      for (int j = 0; j < 4; ++j)
        b_[j] = *(const short8*)&sB[s][(wn * 64 + j * 16 + l16) * 64 + ((kk + quad * 8) ^ swx)];
#pragma unroll
      for (int i = 0; i < 2; ++i)
#pragma unroll
        for (int j = 0; j < 4; ++j)
          acc[i][j] = __builtin_amdgcn_mfma_f32_16x16x32_bf16(a_[i], b_[j], acc[i][j], 0, 0, 0);
    }

    __builtin_amdgcn_sched_barrier(0);
    __builtin_amdgcn_s_barrier();        // barrier2: all done reading slot s
  }

  if (EPI == 1) {
    // final projection: fp32 C0[M,N]
#pragma unroll
    for (int j = 0; j < 4; ++j) {
      const int colg = bn * 128 + wn * 64 + j * 16 + l16;
      const float bv = __bfloat162float(bias[colg]);
#pragma unroll
      for (int i = 0; i < 2; ++i)
#pragma unroll
        for (int r = 0; r < 4; ++r) {
          int rowg = bm * 128 + wm * 32 + i * 16 + quad * 4 + r;
          ((float*)C0)[(size_t)rowg * N + colg] = acc[i][j][r] + bv;
        }
    }
  } else {
    // QKV split: bn 0..7 -> Qp (C0), 8..15 -> Kp (C1), 16..23 -> Vt (C2)
    const int region = bn >> 3;
    if (region < 2) {
      bf16* dst = (bf16*)(region == 0 ? C0 : C1);
#pragma unroll
      for (int j = 0; j < 4; ++j) {
        const int colg = bn * 128 + wn * 64 + j * 16 + l16;        // 0..3071
        const int colr = colg & 1023;                              // col in region
        const float bv = __bfloat162float(bias[colg]);
#pragma unroll
        for (int i = 0; i < 2; ++i)
#pragma unroll
          for (int r = 0; r < 4; ++r) {
            int rowg = bm * 128 + wm * 32 + i * 16 + quad * 4 + r;
            dst[(size_t)rowg * 1024 + colr] = __float2bfloat16(acc[i][j][r] + bv);
          }
      }
    } else {
      // V transposed: Vt[(b*16+h)<<16 | d*1024 | t], r-packed b64 stores
      bf16* vt = (bf16*)C2;
#pragma unroll
      for (int j = 0; j < 4; ++j) {
        const int colg = bn * 128 + wn * 64 + j * 16 + l16;
        const int d  = colg & 63;
        const int hh = (colg >> 6) & 15;
        const float bv = __bfloat162float(bias[colg]);
#pragma unroll
        for (int i = 0; i < 2; ++i) {
          int rowg0 = bm * 128 + wm * 32 + i * 16 + quad * 4;
          int bb = rowg0 >> 10, t0 = rowg0 & 1023;
          short4v pk;
#pragma unroll
          for (int r = 0; r < 4; ++r) pk[r] = (short)f2b_bits(acc[i][j][r] + bv);
          *(short4v*)&vt[((size_t)(bb * 16 + hh) << 16) + ((size_t)d << 10) + t0] = pk;
        }
      }
    }
  }
}

// ---------------------------------------------------------------------------
// Fused attention. grid = (16, 8, 8), 512 threads (8 waves x 16 rows),
// LDS 36.0KB. Work swizzle: bid -> b=bid&7 (XCD), h=(bid>>3)&15 (fastest,
// adj-sharing blocks contiguous on one XCD), qt=bid>>7.
// Q fragments in registers (loop-invariant). K and V^T register-staged into
// stride-72 LDS (balanced banks), software-pipelined across kt.
// sigma(n)=(n&15)*4+(n>>4) on K rows => logical score col = l16*4+j:
// float4 adj/mask loads. p=fast_exp2(clamp(fma(sacc, avc, off))) with
// avc = av*cjv (folded scale); pack via v_cvt_pk_bf16_f32 (RNE) pairs,
// b64 sP stores. L row-sums via ones-column MFMA accumulated across kt.
// ---------------------------------------------------------------------------
__global__ __launch_bounds__(512)
void attn_fused(const bf16* __restrict__ Qp, const bf16* __restrict__ Kp,
                const bf16* __restrict__ Vt, const float* __restrict__ adj,
                const float* __restrict__ mask, bf16* __restrict__ aout)
{
  __shared__ __align__(16) unsigned short sK[64 * 72];
  __shared__ __align__(16) unsigned short sVT[64 * 72];
  __shared__ __align__(16) unsigned short sP[128 * 72];

  const int tid  = threadIdx.x;
  const int lane = tid & 63;
  const int wv   = tid >> 6;          // 0..7
  const int quad = lane >> 4;
  const int l16  = lane & 15;

  // work swizzle: adj-sharing (b,qt) groups contiguous per XCD, K/V[b] local
  const int bid  = blockIdx.x + 16 * (blockIdx.y + 8 * blockIdx.z);
  const int b    = bid & 7;
  const int slot = bid >> 3;
  const int h    = slot & 15;
  const int qt   = slot >> 4;

  // Q fragments: rows qt*128 + wv*16 + l16, k = kk + quad*8 + [0..7]
  const bf16* qbase = Qp + (size_t)(b * T_ + qt * 128 + wv * 16 + l16) * 1024 + h * 64 + quad * 8;
  const short8 aq0 = *(const short8*)qbase;
  const short8 aq1 = *(const short8*)(qbase + 32);

  // staging: 512 threads cover 64 rows x 8 chunks, one 16B chunk each
  const int srow  = tid >> 3;                          // 0..63
  const int chunk = (tid & 7) * 8;
  const int sig = ((srow & 15) << 2) | (srow >> 4);    // token offset for sK row
  const bf16* kb = Kp + (size_t)(b * T_ + sig) * 1024 + h * 64 + chunk;  // +kt<<16
  const bf16* vb = Vt + ((size_t)(b * 16 + h) << 16) + ((size_t)srow << 10) + chunk; // +kt*64

  // adj/mask row pointers
  const float* mb = mask + b * T_ + l16 * 4;
  const float* adjr[4];
#pragma unroll
  for (int r = 0; r < 4; ++r)
    adjr[r] = adj + ((size_t)b * T_ + qt * 128 + wv * 16 + quad * 4 + r) * T_ + l16 * 4;

  // preload kt=0 staging registers
  short8 kr = *(const short8*)kb;
  short8 vr = *(const short8*)vb;

  // bf16 1.0 fragment for L row-sums via MFMA
  short8 ones8;
#pragma unroll
  for (int i = 0; i < 8; ++i) ones8[i] = (short)0x3F80;

  floatx4 oacc[4];
#pragma unroll
  for (int d = 0; d < 4; ++d) oacc[d] = (floatx4){0.f, 0.f, 0.f, 0.f};
  floatx4 Lacc = (floatx4){0.f, 0.f, 0.f, 0.f};

  const float SC = 0.125f * 1.44269504088896f;   // (1/sqrt(dh)) * log2(e)

  for (int kt = 0; kt < 16; ++kt) {
    // adj/mask for this tile (logical cols kt*64 + l16*4 + {0..3})
    floatx4 av[4];
    floatx4 mk4 = *(const floatx4*)(mb + kt * 64);
#pragma unroll
    for (int r = 0; r < 4; ++r) av[r] = *(const floatx4*)(adjr[r] + kt * 64);
    floatx4 cjv, offv;
#pragma unroll
    for (int j = 0; j < 4; ++j) {
      cjv[j]  = mk4[j] * SC;
      offv[j] = (mk4[j] == 0.f) ? -1e30f : 0.f;
    }

    __syncthreads();   // sync1: all waves done reading sK/sVT of prev kt
    *(short8*)&sK [srow * 72 + chunk] = kr;
    *(short8*)&sVT[srow * 72 + chunk] = vr;
    __syncthreads();   // sync2: staging visible

    // prefetch next kt's staging registers (VMEM overlaps compute below)
    {
      int nk = kt < 15 ? kt + 1 : 15;
      kr = *(const short8*)(kb + ((size_t)nk << 16));
      vr = *(const short8*)(vb + (nk << 6));
    }

    // S = Q K^T  (sacc[j][r]: row wv*16+quad*4+r, logical col l16*4+j)
    floatx4 sacc[4];
#pragma unroll
    for (int j = 0; j < 4; ++j) sacc[j] = (floatx4){0.f, 0.f, 0.f, 0.f};
    __builtin_amdgcn_s_setprio(1);
#pragma unroll
    for (int kk = 0; kk < 64; kk += 32) {
      short8 aq = kk ? aq1 : aq0;
#pragma unroll
      for (int j = 0; j < 4; ++j) {
        short8 bk = *(const short8*)&sK[(j * 16 + l16) * 72 + kk + quad * 8];
        sacc[j] = __builtin_amdgcn_mfma_f32_16x16x32_bf16(aq, bk, sacc[j], 0, 0, 0);
      }
    }
    __builtin_amdgcn_s_setprio(0);

    // p = fast_exp2(clamp(fma(sacc, avc, off))); pack via v_cvt_pk_bf16_f32
#pragma unroll
    for (int r = 0; r < 4; ++r) {
      floatx4 avc = av[r] * cjv;      // folded adj*mask*SC (pk-pairable)
      float p[4];
#pragma unroll
      for (int j = 0; j < 4; ++j) {
        float z = fminf(fmaf(sacc[j][r], avc[j], offv[j]), 100.f);
        p[j] = fast_exp2(z);
      }
      unsigned w0, w1;
      asm("v_cvt_pk_bf16_f32 %0, %1, %2" : "=v"(w0) : "v"(p[0]), "v"(p[1]));
      asm("v_cvt_pk_bf16_f32 %0, %1, %2" : "=v"(w1) : "v"(p[2]), "v"(p[3]));
      uint2v pw; pw[0] = w0; pw[1] = w1;
      *(uint2v*)&sP[(wv * 16 + quad * 4 + r) * 72 + l16 * 4] = pw;
    }

    // sP rows wave-local; same-wave DS is HW-ordered. Stop compiler reorder:
    __asm__ __volatile__("" ::: "memory");

    // O += P V ; L += P * ones
    __builtin_amdgcn_s_setprio(1);
#pragma unroll
    for (int kk = 0; kk < 64; kk += 32) {
      short8 ap = *(const short8*)&sP[(wv * 16 + l16) * 72 + kk + quad * 8];
      Lacc = __builtin_amdgcn_mfma_f32_16x16x32_bf16(ap, ones8, Lacc, 0, 0, 0);
#pragma unroll
      for (int d = 0; d < 4; ++d) {
        short8 bv = *(const short8*)&sVT[(d * 16 + l16) * 72 + kk + quad * 8];
        oacc[d] = __builtin_amdgcn_mfma_f32_16x16x32_bf16(ap, bv, oacc[d], 0, 0, 0);
      }
    }
    __builtin_amdgcn_s_setprio(0);
  }

  // epilogue: Lacc[r] already holds the full row sum (every col identical)
#pragma unroll
  for (int d = 0; d < 4; ++d) {
#pragma unroll
    for (int r = 0; r < 4; ++r) {
      int qrow = qt * 128 + wv * 16 + quad * 4 + r;
      float val = oacc[d][r] / (Lacc[r] + 1e-13f);
      aout[(size_t)(b * T_ + qrow) * 1024 + h * 64 + d * 16 + l16] = __float2bfloat16(val);
    }
  }
}

// ---------------------------------------------------------------------------
extern "C" void kernel_launch(void* const* d_in, const int* in_sizes, int n_in,
                              void* d_out, int out_size, void* d_ws, size_t ws_size,
                              hipStream_t stream) {
  const float* inputs = (const float*)d_in[0];   // [8,1024,1024]
  const float* mask   = (const float*)d_in[1];   // [8,1024]
  const float* adj    = (const float*)d_in[2];   // [8,1024,1024]
  const float* W_qkv  = (const float*)d_in[3];   // [3072,1024]
  const float* b_qkv  = (const float*)d_in[4];   // [3072]
  const float* W_out  = (const float*)d_in[5];   // [1024,1024]
  const float* b_out  = (const float*)d_in[6];   // [1024]

  const size_t SEG = (size_t)8192 * 1024;        // 16 MiB bf16 segments
  bf16* Qp   = (bf16*)d_ws;                      // @0
  bf16* Kp   = Qp + SEG;                         // @16MiB
  bf16* Vt   = Kp + SEG;                         // @32MiB
  bf16* aout = Vt + SEG;                         // @48MiB
  bf16* wo_bf = Qp;                              // Qp dead after attn
  bf16* bo_bf = Qp + (size_t)1024 * 1024;

  // d_out as phase-1 scratch (32MiB fp32 region, dead until GEMM3)
  bf16* ib_bf = (bf16*)d_out;                    // 16MiB
  bf16* wq_bf = ib_bf + SEG;                     // 6MiB
  bf16* bq_bf = wq_bf + (size_t)3072 * 1024;

  dim3 blk(256);
  cvt_f32_bf16<<<dim3(8192 * 1024 / 4 / 256), blk, 0, stream>>>(inputs, ib_bf, 8192 * 1024);
  cvt_f32_bf16<<<dim3(3072 * 1024 / 4 / 256), blk, 0, stream>>>(W_qkv, wq_bf, 3072 * 1024);
  cvt_f32_bf16<<<dim3(3), blk, 0, stream>>>(b_qkv, bq_bf, 3072);
  // QKV projection with split epilogue (Qp, Kp, Vt) — 512-thread blocks
  gemm_bt_bias<2><<<dim3(PROJW / 128, (B_ * T_) / 128), dim3(512), 0, stream>>>(
      ib_bf, wq_bf, bq_bf, Qp, Kp, Vt, B_ * T_, PROJW, D_);
  // fused attention (512 threads, 128 q-rows/block)
  attn_fused<<<dim3(H_, T_ / 128, B_), dim3(512), 0, stream>>>(Qp, Kp, Vt, adj, mask, aout);
  // output projection weights into dead Qp region
  cvt_f32_bf16<<<dim3(1024 * 1024 / 4 / 256), blk, 0, stream>>>(W_out, wo_bf, 1024 * 1024);
  cvt_f32_bf16<<<dim3(1), blk, 0, stream>>>(b_out, bo_bf, 1024);
  // output projection: C fp32 -> d_out — 512-thread blocks
  gemm_bt_bias<1><<<dim3(D_ / 128, (B_ * T_) / 128), dim3(512), 0, stream>>>(
      aout, wo_bf, bo_bf, d_out, nullptr, nullptr, B_ * T_, D_, D_);
}